// Round 1
// baseline (1040.152 us; speedup 1.0000x reference)
//
#include <hip/hip_runtime.h>
#include <math.h>

// Problem constants
#define H_    8
#define DH    64
#define NN    512
#define KADJ  16
#define FF    512      // H_*DH
#define BTOT  24       // B*T
#define ROWS  12288    // B*T*N
#define SN_   27
#define EPS_  1e-5f

// ---------------------------------------------------------------------------
// Kernel 1: x_ = x + (spa_vec*spa_val + tem_vec*tem_val)   (float4 vectorized)
// ---------------------------------------------------------------------------
__global__ __launch_bounds__(256) void add_pos_kernel(
    const float* __restrict__ x,
    const float* __restrict__ spa_val, const float* __restrict__ spa_vec,
    const float* __restrict__ tem_val, const float* __restrict__ tem_vec,
    float* __restrict__ xo)
{
    int i = blockIdx.x * blockDim.x + threadIdx.x;   // float4 index
    const int total4 = ROWS * FF / 4;                // 1,572,864
    if (i >= total4) return;
    int f4  = i & 127;                 // FF/4 = 128
    int row = i >> 7;                  // 0..12287
    int n   = row & (NN - 1);

    float4 xv = reinterpret_cast<const float4*>(x)[i];
    float4 sv = reinterpret_cast<const float4*>(spa_vec)[n * 128 + f4];
    float4 tv = reinterpret_cast<const float4*>(tem_vec)[n * 128 + f4];
    float4 se = reinterpret_cast<const float4*>(spa_val)[f4];
    float4 te = reinterpret_cast<const float4*>(tem_val)[f4];
    float4 r;
    r.x = xv.x + sv.x * se.x + tv.x * te.x;
    r.y = xv.y + sv.y * se.y + tv.y * te.y;
    r.z = xv.z + sv.z * se.z + tv.z * te.z;
    r.w = xv.w + sv.w * se.w + tv.w * te.w;
    reinterpret_cast<float4*>(xo)[i] = r;
}

// ---------------------------------------------------------------------------
// Kernel 2: fp32 tiled GEMM  C[M,512] = A[M,512] * W[512,512]^T + bias
// EPI: 0 = none, 1 = relu, 2 = add residual (addsrc)
// ---------------------------------------------------------------------------
#define BM 64
#define BN 64
#define BK 16

template <int EPI>
__global__ __launch_bounds__(256) void gemm_fp32(
    const float* __restrict__ A, const float* __restrict__ W,
    const float* __restrict__ bias, const float* __restrict__ addsrc,
    float* __restrict__ C)
{
    __shared__ float As[BK][BM + 1];
    __shared__ float Ws[BK][BN + 1];

    const int tid = threadIdx.x;          // 0..255
    const int tx  = tid & 15;
    const int ty  = tid >> 4;
    const int rowBase = blockIdx.y * BM;
    const int colBase = blockIdx.x * BN;

    float acc[4][4] = {};

    const int lr = tid >> 2;              // 0..63 (tile row)
    const int kq = (tid & 3) * 4;         // 0,4,8,12

    for (int k0 = 0; k0 < FF; k0 += BK) {
        float4 a4 = *reinterpret_cast<const float4*>(
            &A[(size_t)(rowBase + lr) * FF + k0 + kq]);
        float4 w4 = *reinterpret_cast<const float4*>(
            &W[(size_t)(colBase + lr) * FF + k0 + kq]);
        As[kq + 0][lr] = a4.x; As[kq + 1][lr] = a4.y;
        As[kq + 2][lr] = a4.z; As[kq + 3][lr] = a4.w;
        Ws[kq + 0][lr] = w4.x; Ws[kq + 1][lr] = w4.y;
        Ws[kq + 2][lr] = w4.z; Ws[kq + 3][lr] = w4.w;
        __syncthreads();

        #pragma unroll
        for (int kk = 0; kk < BK; ++kk) {
            float a[4], b[4];
            #pragma unroll
            for (int i = 0; i < 4; ++i) a[i] = As[kk][ty + 16 * i];
            #pragma unroll
            for (int j = 0; j < 4; ++j) b[j] = Ws[kk][tx + 16 * j];
            #pragma unroll
            for (int i = 0; i < 4; ++i)
                #pragma unroll
                for (int j = 0; j < 4; ++j) acc[i][j] += a[i] * b[j];
        }
        __syncthreads();
    }

    #pragma unroll
    for (int i = 0; i < 4; ++i) {
        const int r = rowBase + ty + 16 * i;
        #pragma unroll
        for (int j = 0; j < 4; ++j) {
            const int c = colBase + tx + 16 * j;
            float v = acc[i][j] + bias[c];
            if (EPI == 1) v = fmaxf(v, 0.0f);
            if (EPI == 2) v += addsrc[(size_t)r * FF + c];
            C[(size_t)r * FF + c] = v;
        }
    }
}

// ---------------------------------------------------------------------------
// Kernel 3: qks + M   (one thread per (h,bt,n))
// M[(h*24+bt)*512+n] = sum_k dot(Q[n], K[adj[n,k]]) * w_proj[k] + b_proj
// ---------------------------------------------------------------------------
__global__ __launch_bounds__(256) void qks_M_kernel(
    const float* __restrict__ Q, const float* __restrict__ K,
    const int* __restrict__ adj, const float* __restrict__ w_proj,
    const float* __restrict__ b_proj, float* __restrict__ Mout)
{
    int idx = blockIdx.x * blockDim.x + threadIdx.x;   // 98304 = 8*24*512
    if (idx >= H_ * BTOT * NN) return;
    const int n   = idx & (NN - 1);
    const int hbt = idx >> 9;
    const int h   = hbt / BTOT;
    const int bt  = hbt % BTOT;

    const float4* q4 = reinterpret_cast<const float4*>(
        Q + ((size_t)(bt * NN + n)) * FF + h * DH);
    float4 qv[16];
    #pragma unroll
    for (int t = 0; t < 16; ++t) qv[t] = q4[t];

    float m = b_proj[0];
    for (int k = 0; k < KADJ; ++k) {
        const int j = adj[n * KADJ + k];
        const float4* k4 = reinterpret_cast<const float4*>(
            K + ((size_t)(bt * NN + j)) * FF + h * DH);
        float d = 0.0f;
        #pragma unroll
        for (int t = 0; t < 16; ++t) {
            float4 kv = k4[t];
            d += qv[t].x * kv.x + qv[t].y * kv.y + qv[t].z * kv.z + qv[t].w * kv.w;
        }
        m += d * w_proj[k];
    }
    Mout[idx] = m;
}

// ---------------------------------------------------------------------------
// Kernel 4: top-27 (descending, ties -> lower index) per group (h,bt)
// one wave per group
// ---------------------------------------------------------------------------
__global__ __launch_bounds__(64) void topk_kernel(
    const float* __restrict__ M, int* __restrict__ mtop)
{
    const int g = blockIdx.x;   // 0..191
    __shared__ float vals[NN];
    const int lane = threadIdx.x;
    for (int i = lane; i < NN; i += 64) vals[i] = M[(size_t)g * NN + i];
    __syncthreads();

    for (int s = 0; s < SN_; ++s) {
        float bv = -INFINITY;
        int bi = 1 << 30;
        for (int i = lane; i < NN; i += 64) {
            float v = vals[i];
            if (v > bv || (v == bv && i < bi)) { bv = v; bi = i; }
        }
        #pragma unroll
        for (int o = 32; o; o >>= 1) {
            float ov = __shfl_xor(bv, o);
            int   oi = __shfl_xor(bi, o);
            if (ov > bv || (ov == bv && oi < bi)) { bv = ov; bi = oi; }
        }
        if (lane == 0) {
            mtop[g * SN_ + s] = bi;
            vals[bi] = -INFINITY;
        }
        __syncthreads();
    }
}

// ---------------------------------------------------------------------------
// Kernel 5: attention per (h,bt) block:
// scores(27x512) -> softmax rows -> cp=argmax over s -> val=attn@V ->
// Out[n, h*64+d] = val[cp[n]][d]
// ---------------------------------------------------------------------------
__global__ __launch_bounds__(256) void attn_kernel(
    const float* __restrict__ Q, const float* __restrict__ K,
    const float* __restrict__ V, const int* __restrict__ mtop,
    float* __restrict__ Out)
{
    __shared__ float sc[SN_][NN];     // 55296 B
    __shared__ float val[SN_][DH];    // 6912 B
    __shared__ int   mt[SN_];
    __shared__ int   cp[NN];          // 2048 B

    const int g  = blockIdx.x;        // h*24 + bt
    const int h  = g / BTOT;
    const int bt = g % BTOT;
    const int tid = threadIdx.x;
    const size_t baseBT = (size_t)bt * NN * FF;

    if (tid < SN_) mt[tid] = mtop[g * SN_ + tid];
    __syncthreads();

    // --- scores = (Qr . K) / 8 ---
    for (int p = tid; p < SN_ * NN; p += 256) {
        const int s = p >> 9;
        const int n = p & (NN - 1);
        const float4* qr = reinterpret_cast<const float4*>(
            Q + baseBT + (size_t)mt[s] * FF + h * DH);
        const float4* kr = reinterpret_cast<const float4*>(
            K + baseBT + (size_t)n * FF + h * DH);
        float d = 0.0f;
        #pragma unroll
        for (int t = 0; t < 16; ++t) {
            float4 a = qr[t], b = kr[t];
            d += a.x * b.x + a.y * b.y + a.z * b.z + a.w * b.w;
        }
        sc[s][n] = d * 0.125f;
    }
    __syncthreads();

    // --- softmax over n per row s (one wave per row, round-robin) ---
    const int wave = tid >> 6, lane = tid & 63;
    for (int s = wave; s < SN_; s += 4) {
        float mx = -INFINITY;
        for (int n = lane; n < NN; n += 64) mx = fmaxf(mx, sc[s][n]);
        #pragma unroll
        for (int o = 32; o; o >>= 1) mx = fmaxf(mx, __shfl_xor(mx, o));
        float ssum = 0.0f;
        for (int n = lane; n < NN; n += 64) {
            float e = expf(sc[s][n] - mx);
            sc[s][n] = e;
            ssum += e;
        }
        #pragma unroll
        for (int o = 32; o; o >>= 1) ssum += __shfl_xor(ssum, o);
        const float inv = 1.0f / ssum;
        for (int n = lane; n < NN; n += 64) sc[s][n] *= inv;
    }
    __syncthreads();

    // --- cp[n] = argmax over s (first occurrence) ---
    for (int n = tid; n < NN; n += 256) {
        float best = sc[0][n];
        int bs = 0;
        for (int s = 1; s < SN_; ++s) {
            float v = sc[s][n];
            if (v > best) { best = v; bs = s; }
        }
        cp[n] = bs;
    }

    // --- val[s][d] = sum_n attn[s][n] * V[n][h*64+d] ---
    for (int p = tid; p < SN_ * DH; p += 256) {
        const int s = p >> 6;
        const int d = p & (DH - 1);
        const float* vcol = V + baseBT + h * DH + d;
        float acc = 0.0f;
        for (int n = 0; n < NN; ++n) acc += sc[s][n] * vcol[(size_t)n * FF];
        val[s][d] = acc;
    }
    __syncthreads();

    // --- scatter: Out[n, h*64+d] = val[cp[n]][d] ---
    for (int p = tid; p < NN * DH; p += 256) {
        const int n = p >> 6;
        const int d = p & (DH - 1);
        Out[baseBT + (size_t)n * FF + h * DH + d] = val[cp[n]][d];
    }
}

// ---------------------------------------------------------------------------
// Kernel 6: LayerNorm over last dim (512). AFFINE=1 applies gamma/beta.
// one wave per row, 4 rows per block
// ---------------------------------------------------------------------------
template <int AFFINE>
__global__ __launch_bounds__(256) void ln_kernel(
    const float* __restrict__ X, const float* __restrict__ g,
    const float* __restrict__ b, float* __restrict__ Y, int rows)
{
    const int row = blockIdx.x * 4 + (threadIdx.x >> 6);
    if (row >= rows) return;
    const int lane = threadIdx.x & 63;
    const float4* x4 = reinterpret_cast<const float4*>(X + (size_t)row * FF);
    float4 a = x4[lane];
    float4 c = x4[lane + 64];
    float s = a.x + a.y + a.z + a.w + c.x + c.y + c.z + c.w;
    float q = a.x * a.x + a.y * a.y + a.z * a.z + a.w * a.w +
              c.x * c.x + c.y * c.y + c.z * c.z + c.w * c.w;
    #pragma unroll
    for (int o = 32; o; o >>= 1) {
        s += __shfl_xor(s, o);
        q += __shfl_xor(q, o);
    }
    const float mu  = s * (1.0f / FF);
    const float var = q * (1.0f / FF) - mu * mu;
    const float rstd = 1.0f / sqrtf(var + EPS_);

    float4 ya, yc;
    ya.x = (a.x - mu) * rstd; ya.y = (a.y - mu) * rstd;
    ya.z = (a.z - mu) * rstd; ya.w = (a.w - mu) * rstd;
    yc.x = (c.x - mu) * rstd; yc.y = (c.y - mu) * rstd;
    yc.z = (c.z - mu) * rstd; yc.w = (c.w - mu) * rstd;
    if (AFFINE) {
        float4 ga = reinterpret_cast<const float4*>(g)[lane];
        float4 gc = reinterpret_cast<const float4*>(g)[lane + 64];
        float4 ba = reinterpret_cast<const float4*>(b)[lane];
        float4 bc = reinterpret_cast<const float4*>(b)[lane + 64];
        ya.x = ya.x * ga.x + ba.x; ya.y = ya.y * ga.y + ba.y;
        ya.z = ya.z * ga.z + ba.z; ya.w = ya.w * ga.w + ba.w;
        yc.x = yc.x * gc.x + bc.x; yc.y = yc.y * gc.y + bc.y;
        yc.z = yc.z * gc.z + bc.z; yc.w = yc.w * gc.w + bc.w;
    }
    float4* y4 = reinterpret_cast<float4*>(Y + (size_t)row * FF);
    y4[lane]      = ya;
    y4[lane + 64] = yc;
}

// ---------------------------------------------------------------------------
// Launch
// ---------------------------------------------------------------------------
extern "C" void kernel_launch(void* const* d_in, const int* in_sizes, int n_in,
                              void* d_out, int out_size, void* d_ws, size_t ws_size,
                              hipStream_t stream)
{
    const float* x       = (const float*)d_in[0];
    const float* spa_val = (const float*)d_in[1];
    const float* spa_vec = (const float*)d_in[2];
    const float* tem_val = (const float*)d_in[3];
    const float* tem_vec = (const float*)d_in[4];
    const int*   adj     = (const int*)  d_in[5];
    const float* Wq = (const float*)d_in[6];  const float* bq = (const float*)d_in[7];
    const float* Wk = (const float*)d_in[8];  const float* bk = (const float*)d_in[9];
    const float* Wv = (const float*)d_in[10]; const float* bv = (const float*)d_in[11];
    const float* Wo = (const float*)d_in[12]; const float* bo = (const float*)d_in[13];
    const float* w_proj = (const float*)d_in[14];
    const float* b_proj = (const float*)d_in[15];
    const float* gamma  = (const float*)d_in[16];
    const float* beta   = (const float*)d_in[17];
    const float* W1 = (const float*)d_in[18]; const float* b1 = (const float*)d_in[19];
    const float* W2 = (const float*)d_in[20]; const float* b2 = (const float*)d_in[21];

    float* out = (float*)d_out;
    float* ws  = (float*)d_ws;

    const size_t R = (size_t)ROWS * FF;   // 6,291,456 floats
    float* bufQ = ws;
    float* bufK = ws + R;
    float* bufV = ws + 2 * R;
    float* Mbuf = ws + 3 * R;                       // 98,304 floats
    int*   mtop = (int*)(ws + 3 * R + H_ * BTOT * NN);  // 5,184 ints

    // x_ -> d_out (scratch use; fully rewritten at the end)
    add_pos_kernel<<<(ROWS * FF / 4 + 255) / 256, 256, 0, stream>>>(
        x, spa_val, spa_vec, tem_val, tem_vec, out);

    dim3 gg(FF / BN, ROWS / BM);   // (8, 192)
    gemm_fp32<0><<<gg, 256, 0, stream>>>(out, Wq, bq, nullptr, bufQ);
    gemm_fp32<0><<<gg, 256, 0, stream>>>(out, Wk, bk, nullptr, bufK);
    gemm_fp32<0><<<gg, 256, 0, stream>>>(out, Wv, bv, nullptr, bufV);

    qks_M_kernel<<<(H_ * BTOT * NN) / 256, 256, 0, stream>>>(
        bufQ, bufK, adj, w_proj, b_proj, Mbuf);

    topk_kernel<<<H_ * BTOT, 64, 0, stream>>>(Mbuf, mtop);

    attn_kernel<<<H_ * BTOT, 256, 0, stream>>>(bufQ, bufK, bufV, mtop, out);

    // out (attn result) -> o = out@Wo^T+bo in bufQ
    gemm_fp32<0><<<gg, 256, 0, stream>>>(out, Wo, bo, nullptr, bufQ);
    // v = LN(o)*gamma+beta in bufK
    ln_kernel<1><<<ROWS / 4, 256, 0, stream>>>(bufQ, gamma, beta, bufK, ROWS);
    // h1 = relu(v@W1^T+b1) in bufV
    gemm_fp32<1><<<gg, 256, 0, stream>>>(bufK, W1, b1, nullptr, bufV);
    // h2 = h1@W2^T+b2 + v in bufQ
    gemm_fp32<2><<<gg, 256, 0, stream>>>(bufV, W2, b2, bufK, bufQ);
    // final LN (no affine) -> d_out
    ln_kernel<0><<<ROWS / 4, 256, 0, stream>>>(bufQ, nullptr, nullptr, out, ROWS);
}

// Round 2
// 550.283 us; speedup vs baseline: 1.8902x; 1.8902x over previous
//
#include <hip/hip_runtime.h>
#include <math.h>

// Problem constants
#define H_    8
#define DH    64
#define NN    512
#define KADJ  16
#define FF    512      // H_*Dh
#define BTOT  24       // B*T
#define ROWS  12288    // B*T*N
#define SN_   27
#define EPS_  1e-5f

typedef short short8 __attribute__((ext_vector_type(8)));
typedef float f32x4  __attribute__((ext_vector_type(4)));

__device__ __forceinline__ ushort f2bf(float x) {
    uint u = __float_as_uint(x);
    u += 0x7FFFu + ((u >> 16) & 1u);
    return (ushort)(u >> 16);
}
__device__ __forceinline__ float bf2f(ushort h) {
    return __uint_as_float(((uint)h) << 16);
}

// ---------------------------------------------------------------------------
// Kernel 1: x_ = x + (spa_vec*spa_val + tem_vec*tem_val)
// ---------------------------------------------------------------------------
__global__ __launch_bounds__(256) void add_pos_kernel(
    const float* __restrict__ x,
    const float* __restrict__ spa_val, const float* __restrict__ spa_vec,
    const float* __restrict__ tem_val, const float* __restrict__ tem_vec,
    float* __restrict__ xo)
{
    int i = blockIdx.x * blockDim.x + threadIdx.x;
    const int total4 = ROWS * FF / 4;
    if (i >= total4) return;
    int f4  = i & 127;
    int row = i >> 7;
    int n   = row & (NN - 1);

    float4 xv = reinterpret_cast<const float4*>(x)[i];
    float4 sv = reinterpret_cast<const float4*>(spa_vec)[n * 128 + f4];
    float4 tv = reinterpret_cast<const float4*>(tem_vec)[n * 128 + f4];
    float4 se = reinterpret_cast<const float4*>(spa_val)[f4];
    float4 te = reinterpret_cast<const float4*>(tem_val)[f4];
    float4 r;
    r.x = xv.x + sv.x * se.x + tv.x * te.x;
    r.y = xv.y + sv.y * se.y + tv.y * te.y;
    r.z = xv.z + sv.z * se.z + tv.z * te.z;
    r.w = xv.w + sv.w * se.w + tv.w * te.w;
    reinterpret_cast<float4*>(xo)[i] = r;
}

// ---------------------------------------------------------------------------
// Kernel 2: MFMA GEMM  C[M,512] = A[M,512] * W[512,512]^T + bias
// SPLIT=1: split-bf16 (3 MFMA, ~fp32 accuracy). SPLIT=0: plain bf16.
// EPI: 0 none, 1 relu, 2 add residual.
// Tile 128x64x32, 256 threads (4 waves, 2m x 2n), wave tile 64x32.
// ---------------------------------------------------------------------------
#define GBM 128
#define GBN 64
#define GBK 32
#define LDP 40   // padded row stride in ushorts (80 B): slot stride 5 mod 8 -> conflict-free

template <int SPLIT, int EPI>
__global__ __launch_bounds__(256) void gemm_mfma(
    const float* __restrict__ A, const float* __restrict__ W,
    const float* __restrict__ bias, const float* __restrict__ addsrc,
    float* __restrict__ C)
{
    __shared__ ushort sAh[GBM * LDP];
    __shared__ ushort sAl[SPLIT ? GBM * LDP : 4];
    __shared__ ushort sWh[GBN * LDP];
    __shared__ ushort sWl[SPLIT ? GBN * LDP : 4];

    const int tid  = threadIdx.x;
    const int lane = tid & 63;
    const int wid  = tid >> 6;
    const int wm   = wid & 1;
    const int wn   = wid >> 1;
    const int rowBase = blockIdx.y * GBM;
    const int colBase = blockIdx.x * GBN;

    const int arow  = tid >> 1;   // 0..127
    const int ahalf = tid & 1;    // 16 floats each
    const int wrow  = tid >> 2;   // 0..63
    const int wq    = tid & 3;    // 8 floats each

    const float* aptr = A + (size_t)(rowBase + arow) * FF + ahalf * 16;
    const float* wptr = W + (size_t)(colBase + wrow) * FF + wq * 8;

    float4 ra[4], rw[2];
    #pragma unroll
    for (int i = 0; i < 4; ++i) ra[i] = ((const float4*)aptr)[i];
    #pragma unroll
    for (int i = 0; i < 2; ++i) rw[i] = ((const float4*)wptr)[i];

    f32x4 acc[4][2];
    #pragma unroll
    for (int mi = 0; mi < 4; ++mi)
        #pragma unroll
        for (int ni = 0; ni < 2; ++ni) acc[mi][ni] = (f32x4){0.f, 0.f, 0.f, 0.f};

    for (int step = 0; step < FF / GBK; ++step) {
        // convert + store staged regs to LDS
        #pragma unroll
        for (int i = 0; i < 4; ++i) {
            float v0 = ra[i].x, v1 = ra[i].y, v2 = ra[i].z, v3 = ra[i].w;
            ushort h0 = f2bf(v0), h1 = f2bf(v1), h2 = f2bf(v2), h3 = f2bf(v3);
            int idx = arow * LDP + ahalf * 16 + i * 4;
            *(ushort4*)(&sAh[idx]) = make_ushort4(h0, h1, h2, h3);
            if (SPLIT) {
                ushort l0 = f2bf(v0 - bf2f(h0)), l1 = f2bf(v1 - bf2f(h1));
                ushort l2 = f2bf(v2 - bf2f(h2)), l3 = f2bf(v3 - bf2f(h3));
                *(ushort4*)(&sAl[idx]) = make_ushort4(l0, l1, l2, l3);
            }
        }
        #pragma unroll
        for (int i = 0; i < 2; ++i) {
            float v0 = rw[i].x, v1 = rw[i].y, v2 = rw[i].z, v3 = rw[i].w;
            ushort h0 = f2bf(v0), h1 = f2bf(v1), h2 = f2bf(v2), h3 = f2bf(v3);
            int idx = wrow * LDP + wq * 8 + i * 4;
            *(ushort4*)(&sWh[idx]) = make_ushort4(h0, h1, h2, h3);
            if (SPLIT) {
                ushort l0 = f2bf(v0 - bf2f(h0)), l1 = f2bf(v1 - bf2f(h1));
                ushort l2 = f2bf(v2 - bf2f(h2)), l3 = f2bf(v3 - bf2f(h3));
                *(ushort4*)(&sWl[idx]) = make_ushort4(l0, l1, l2, l3);
            }
        }
        __syncthreads();

        // prefetch next k-tile into regs (overlaps MFMA below)
        if (step < FF / GBK - 1) {
            const float* ap = aptr + (step + 1) * GBK;
            const float* wp = wptr + (step + 1) * GBK;
            #pragma unroll
            for (int i = 0; i < 4; ++i) ra[i] = ((const float4*)ap)[i];
            #pragma unroll
            for (int i = 0; i < 2; ++i) rw[i] = ((const float4*)wp)[i];
        }

        // fragments + MFMA
        const int kc = (lane >> 4) * 8;
        short8 afh[4], afl[4], wfh[2], wfl[2];
        #pragma unroll
        for (int mi = 0; mi < 4; ++mi) {
            int r = wm * 64 + mi * 16 + (lane & 15);
            afh[mi] = *(const short8*)(&sAh[r * LDP + kc]);
            if (SPLIT) afl[mi] = *(const short8*)(&sAl[r * LDP + kc]);
        }
        #pragma unroll
        for (int ni = 0; ni < 2; ++ni) {
            int r = wn * 32 + ni * 16 + (lane & 15);
            wfh[ni] = *(const short8*)(&sWh[r * LDP + kc]);
            if (SPLIT) wfl[ni] = *(const short8*)(&sWl[r * LDP + kc]);
        }
        #pragma unroll
        for (int mi = 0; mi < 4; ++mi)
            #pragma unroll
            for (int ni = 0; ni < 2; ++ni) {
                acc[mi][ni] = __builtin_amdgcn_mfma_f32_16x16x32_bf16(
                    afh[mi], wfh[ni], acc[mi][ni], 0, 0, 0);
                if (SPLIT) {
                    acc[mi][ni] = __builtin_amdgcn_mfma_f32_16x16x32_bf16(
                        afh[mi], wfl[ni], acc[mi][ni], 0, 0, 0);
                    acc[mi][ni] = __builtin_amdgcn_mfma_f32_16x16x32_bf16(
                        afl[mi], wfh[ni], acc[mi][ni], 0, 0, 0);
                }
            }
        __syncthreads();
    }

    // epilogue: C/D layout col=lane&15, row=(lane>>4)*4+reg
    #pragma unroll
    for (int mi = 0; mi < 4; ++mi)
        #pragma unroll
        for (int ni = 0; ni < 2; ++ni) {
            const int col = colBase + wn * 32 + ni * 16 + (lane & 15);
            const float bcol = bias[col];
            #pragma unroll
            for (int r = 0; r < 4; ++r) {
                const int row = rowBase + wm * 64 + mi * 16 + (lane >> 4) * 4 + r;
                float v = acc[mi][ni][r] + bcol;
                if (EPI == 1) v = fmaxf(v, 0.0f);
                if (EPI == 2) v += addsrc[(size_t)row * FF + col];
                C[(size_t)row * FF + col] = v;
            }
        }
}

// ---------------------------------------------------------------------------
// Kernel 3: qks + M, wave per (h,bt,n):
// t_d = q_d * sum_k w_k * K[adj[n,k]][d]  ->  64-lane reduce
// ---------------------------------------------------------------------------
__global__ __launch_bounds__(256) void qks_M_kernel(
    const float* __restrict__ Q, const float* __restrict__ K,
    const int* __restrict__ adj, const float* __restrict__ w_proj,
    const float* __restrict__ b_proj, float* __restrict__ Mout)
{
    const int w = blockIdx.x * 4 + (threadIdx.x >> 6);   // 0..98303
    const int lane = threadIdx.x & 63;                   // = d
    const int n   = w & (NN - 1);
    const int hbt = w >> 9;
    const int h   = hbt / BTOT;
    const int bt  = hbt % BTOT;

    const size_t base = (size_t)bt * NN * FF + h * DH + lane;
    float s = 0.0f;
    #pragma unroll
    for (int k = 0; k < KADJ; ++k) {
        const int j = adj[n * KADJ + k];
        s += w_proj[k] * K[base + (size_t)j * FF - lane + lane];  // K[(bt*NN+j)*FF + h*DH + lane]
    }
    // fix addressing explicitly (avoid the confusing expr above)
    // (recompute cleanly below)
    s = 0.0f;
    #pragma unroll
    for (int k = 0; k < KADJ; ++k) {
        const int j = adj[n * KADJ + k];
        s += w_proj[k] * K[((size_t)(bt * NN + j)) * FF + h * DH + lane];
    }
    float t = Q[((size_t)(bt * NN + n)) * FF + h * DH + lane] * s;
    #pragma unroll
    for (int o = 32; o; o >>= 1) t += __shfl_xor(t, o);
    if (lane == 0) Mout[(size_t)hbt * NN + n] = t + b_proj[0];
}

// ---------------------------------------------------------------------------
// Kernel 4: top-27 per group (h,bt), one wave per group
// ---------------------------------------------------------------------------
__global__ __launch_bounds__(64) void topk_kernel(
    const float* __restrict__ M, int* __restrict__ mtop)
{
    const int g = blockIdx.x;
    __shared__ float vals[NN];
    const int lane = threadIdx.x;
    for (int i = lane; i < NN; i += 64) vals[i] = M[(size_t)g * NN + i];
    __syncthreads();

    for (int s = 0; s < SN_; ++s) {
        float bv = -INFINITY;
        int bi = 1 << 30;
        for (int i = lane; i < NN; i += 64) {
            float v = vals[i];
            if (v > bv || (v == bv && i < bi)) { bv = v; bi = i; }
        }
        #pragma unroll
        for (int o = 32; o; o >>= 1) {
            float ov = __shfl_xor(bv, o);
            int   oi = __shfl_xor(bi, o);
            if (ov > bv || (ov == bv && oi < bi)) { bv = ov; bi = oi; }
        }
        if (lane == 0) {
            mtop[g * SN_ + s] = bi;
            vals[bi] = -INFINITY;
        }
        __syncthreads();
    }
}

// ---------------------------------------------------------------------------
// Kernel 5a: scores + softmax. block = (s, g); 256 threads, 2 n each.
// probs[(g*27+s)*512+n]
// ---------------------------------------------------------------------------
__global__ __launch_bounds__(256) void score_softmax_kernel(
    const float* __restrict__ Q, const float* __restrict__ K,
    const int* __restrict__ mtop, float* __restrict__ probs)
{
    __shared__ float qs[DH];
    __shared__ float red[4];

    const int s = blockIdx.x;
    const int g = blockIdx.y;
    const int h  = g / BTOT;
    const int bt = g % BTOT;
    const int tid = threadIdx.x;
    const int wid = tid >> 6, lane = tid & 63;

    const int mt = mtop[g * SN_ + s];
    if (tid < DH)
        qs[tid] = Q[((size_t)(bt * NN + mt)) * FF + h * DH + tid];
    __syncthreads();

    const int n0 = tid, n1 = tid + 256;
    float sc0 = 0.f, sc1 = 0.f;
    {
        const float4* kr0 = reinterpret_cast<const float4*>(
            K + ((size_t)(bt * NN + n0)) * FF + h * DH);
        const float4* kr1 = reinterpret_cast<const float4*>(
            K + ((size_t)(bt * NN + n1)) * FF + h * DH);
        const float4* q4 = reinterpret_cast<const float4*>(qs);
        #pragma unroll
        for (int t = 0; t < 16; ++t) {
            float4 q = q4[t], a = kr0[t], b = kr1[t];
            sc0 += q.x * a.x + q.y * a.y + q.z * a.z + q.w * a.w;
            sc1 += q.x * b.x + q.y * b.y + q.z * b.z + q.w * b.w;
        }
    }
    sc0 *= 0.125f; sc1 *= 0.125f;

    // block max
    float mx = fmaxf(sc0, sc1);
    #pragma unroll
    for (int o = 32; o; o >>= 1) mx = fmaxf(mx, __shfl_xor(mx, o));
    if (lane == 0) red[wid] = mx;
    __syncthreads();
    mx = fmaxf(fmaxf(red[0], red[1]), fmaxf(red[2], red[3]));
    __syncthreads();

    float e0 = expf(sc0 - mx), e1 = expf(sc1 - mx);
    float ssum = e0 + e1;
    #pragma unroll
    for (int o = 32; o; o >>= 1) ssum += __shfl_xor(ssum, o);
    if (lane == 0) red[wid] = ssum;
    __syncthreads();
    const float inv = 1.0f / (red[0] + red[1] + red[2] + red[3]);

    float* prow = probs + ((size_t)g * SN_ + s) * NN;
    prow[n0] = e0 * inv;
    prow[n1] = e1 * inv;
}

// ---------------------------------------------------------------------------
// Kernel 5b: cp[n] = argmax over s (first max)
// ---------------------------------------------------------------------------
__global__ __launch_bounds__(256) void cp_argmax_kernel(
    const float* __restrict__ probs, int* __restrict__ cp)
{
    const int i = blockIdx.x * 256 + threadIdx.x;   // 98304
    const int g = i >> 9, n = i & (NN - 1);
    const float* p = probs + (size_t)g * SN_ * NN + n;
    float best = p[0];
    int bs = 0;
    #pragma unroll
    for (int s = 1; s < SN_; ++s) {
        float v = p[(size_t)s * NN];
        if (v > best) { best = v; bs = s; }
    }
    cp[i] = bs;
}

// ---------------------------------------------------------------------------
// Kernel 5c: val[g][s][d] = sum_n probs[g][s][n] * V[bt][n][h*64+d]
// block = (s, g); 256 threads = 64 d x 4 n-quarters; LDS reduce
// ---------------------------------------------------------------------------
__global__ __launch_bounds__(256) void val_kernel(
    const float* __restrict__ probs, const float* __restrict__ V,
    float* __restrict__ val)
{
    __shared__ float part[256];
    const int s = blockIdx.x;
    const int g = blockIdx.y;
    const int h  = g / BTOT;
    const int bt = g % BTOT;
    const int tid = threadIdx.x;
    const int d  = tid & 63;
    const int qq = tid >> 6;

    const float* prow = probs + ((size_t)g * SN_ + s) * NN;
    const float* vcol = V + (size_t)bt * NN * FF + h * DH + d;
    float acc = 0.f;
    const int nb = qq * 128;
    for (int n = nb; n < nb + 128; ++n)
        acc += prow[n] * vcol[(size_t)n * FF];
    part[tid] = acc;
    __syncthreads();
    if (tid < 64)
        val[((size_t)g * SN_ + s) * DH + tid] =
            part[tid] + part[tid + 64] + part[tid + 128] + part[tid + 192];
}

// ---------------------------------------------------------------------------
// Kernel 5d: scatter: attnout[bt][n][h*64+d4] = val[g][cp[g][n]][d4]
// ---------------------------------------------------------------------------
__global__ __launch_bounds__(256) void scatter_kernel(
    const float* __restrict__ val, const int* __restrict__ cp,
    float* __restrict__ attnout)
{
    const int i = blockIdx.x * 256 + threadIdx.x;   // 1,572,864 float4 slots
    const int d4 = i & 15;
    const int n  = (i >> 4) & (NN - 1);
    const int g  = i >> 13;
    const int h  = g / BTOT;
    const int bt = g % BTOT;
    const int c  = cp[g * NN + n];
    float4 v = reinterpret_cast<const float4*>(val)[((size_t)g * SN_ + c) * 16 + d4];
    reinterpret_cast<float4*>(attnout)[((size_t)(bt * NN + n)) * 128 + h * 16 + d4] = v;
}

// ---------------------------------------------------------------------------
// Kernel 6: LayerNorm over last dim (512)
// ---------------------------------------------------------------------------
template <int AFFINE>
__global__ __launch_bounds__(256) void ln_kernel(
    const float* __restrict__ X, const float* __restrict__ g,
    const float* __restrict__ b, float* __restrict__ Y, int rows)
{
    const int row = blockIdx.x * 4 + (threadIdx.x >> 6);
    if (row >= rows) return;
    const int lane = threadIdx.x & 63;
    const float4* x4 = reinterpret_cast<const float4*>(X + (size_t)row * FF);
    float4 a = x4[lane];
    float4 c = x4[lane + 64];
    float s = a.x + a.y + a.z + a.w + c.x + c.y + c.z + c.w;
    float q = a.x * a.x + a.y * a.y + a.z * a.z + a.w * a.w +
              c.x * c.x + c.y * c.y + c.z * c.z + c.w * c.w;
    #pragma unroll
    for (int o = 32; o; o >>= 1) {
        s += __shfl_xor(s, o);
        q += __shfl_xor(q, o);
    }
    const float mu  = s * (1.0f / FF);
    const float var = q * (1.0f / FF) - mu * mu;
    const float rstd = 1.0f / sqrtf(var + EPS_);

    float4 ya, yc;
    ya.x = (a.x - mu) * rstd; ya.y = (a.y - mu) * rstd;
    ya.z = (a.z - mu) * rstd; ya.w = (a.w - mu) * rstd;
    yc.x = (c.x - mu) * rstd; yc.y = (c.y - mu) * rstd;
    yc.z = (c.z - mu) * rstd; yc.w = (c.w - mu) * rstd;
    if (AFFINE) {
        float4 ga = reinterpret_cast<const float4*>(g)[lane];
        float4 gc = reinterpret_cast<const float4*>(g)[lane + 64];
        float4 ba = reinterpret_cast<const float4*>(b)[lane];
        float4 bc = reinterpret_cast<const float4*>(b)[lane + 64];
        ya.x = ya.x * ga.x + ba.x; ya.y = ya.y * ga.y + ba.y;
        ya.z = ya.z * ga.z + ba.z; ya.w = ya.w * ga.w + ba.w;
        yc.x = yc.x * gc.x + bc.x; yc.y = yc.y * gc.y + bc.y;
        yc.z = yc.z * gc.z + bc.z; yc.w = yc.w * gc.w + bc.w;
    }
    float4* y4 = reinterpret_cast<float4*>(Y + (size_t)row * FF);
    y4[lane]      = ya;
    y4[lane + 64] = yc;
}

// ---------------------------------------------------------------------------
// Launch
// ---------------------------------------------------------------------------
extern "C" void kernel_launch(void* const* d_in, const int* in_sizes, int n_in,
                              void* d_out, int out_size, void* d_ws, size_t ws_size,
                              hipStream_t stream)
{
    const float* x       = (const float*)d_in[0];
    const float* spa_val = (const float*)d_in[1];
    const float* spa_vec = (const float*)d_in[2];
    const float* tem_val = (const float*)d_in[3];
    const float* tem_vec = (const float*)d_in[4];
    const int*   adj     = (const int*)  d_in[5];
    const float* Wq = (const float*)d_in[6];  const float* bq = (const float*)d_in[7];
    const float* Wk = (const float*)d_in[8];  const float* bk = (const float*)d_in[9];
    const float* Wv = (const float*)d_in[10]; const float* bv = (const float*)d_in[11];
    const float* Wo = (const float*)d_in[12]; const float* bo = (const float*)d_in[13];
    const float* w_proj = (const float*)d_in[14];
    const float* b_proj = (const float*)d_in[15];
    const float* gamma  = (const float*)d_in[16];
    const float* beta   = (const float*)d_in[17];
    const float* W1 = (const float*)d_in[18]; const float* b1 = (const float*)d_in[19];
    const float* W2 = (const float*)d_in[20]; const float* b2 = (const float*)d_in[21];

    float* out = (float*)d_out;
    float* ws  = (float*)d_ws;

    const size_t R = (size_t)ROWS * FF;   // 6,291,456 floats
    float* bufQ = ws;
    float* bufK = ws + R;
    float* bufV = ws + 2 * R;

    // scratch regions inside d_out (dead between x_ consumption and final LN):
    float* probs = out;                               // 192*27*512 = 2,654,208
    float* valb  = out + 2654208;                     // 192*27*64  =   331,776
    int*   cp    = (int*)(out + 2654208 + 331776);    // 98,304 ints
    float* Mbuf  = out + 2654208 + 331776 + 98304;    // 98,304 floats
    int*   mtop  = (int*)(out + 2654208 + 331776 + 98304 + 98304); // 5,184 ints

    // 1. x_ -> out
    add_pos_kernel<<<(ROWS * FF / 4 + 255) / 256, 256, 0, stream>>>(
        x, spa_val, spa_vec, tem_val, tem_vec, out);

    // 2. Q/K/V projections (Q,K split-precision; V plain bf16)
    dim3 gg(FF / GBN, ROWS / GBM);   // (8, 96)
    gemm_mfma<1, 0><<<gg, 256, 0, stream>>>(out, Wq, bq, nullptr, bufQ);
    gemm_mfma<1, 0><<<gg, 256, 0, stream>>>(out, Wk, bk, nullptr, bufK);
    gemm_mfma<0, 0><<<gg, 256, 0, stream>>>(out, Wv, bv, nullptr, bufV);

    // 3. M scores (x_ in out now dead; Mbuf lives in out)
    qks_M_kernel<<<(H_ * BTOT * NN) / 4, 256, 0, stream>>>(
        bufQ, bufK, adj, w_proj, b_proj, Mbuf);

    // 4. top-27
    topk_kernel<<<H_ * BTOT, 64, 0, stream>>>(Mbuf, mtop);

    // 5. attention
    dim3 sg(SN_, H_ * BTOT);
    score_softmax_kernel<<<sg, 256, 0, stream>>>(bufQ, bufK, mtop, probs);
    cp_argmax_kernel<<<(H_ * BTOT * NN) / 256, 256, 0, stream>>>(probs, cp);
    val_kernel<<<sg, 256, 0, stream>>>(probs, bufV, valb);
    // attnout -> bufQ (Q dead after score kernel)
    scatter_kernel<<<(H_ * BTOT * NN * 16) / 256, 256, 0, stream>>>(valb, cp, bufQ);

    // 6. output projection + LN + FFN
    gemm_mfma<0, 0><<<gg, 256, 0, stream>>>(bufQ, Wo, bo, nullptr, bufK);   // o
    ln_kernel<1><<<ROWS / 4, 256, 0, stream>>>(bufK, gamma, beta, bufV, ROWS); // v
    gemm_mfma<0, 1><<<gg, 256, 0, stream>>>(bufV, W1, b1, nullptr, bufK);   // h1 = relu
    gemm_mfma<0, 2><<<gg, 256, 0, stream>>>(bufK, W2, b2, bufV, bufQ);      // h2 = +v
    ln_kernel<0><<<ROWS / 4, 256, 0, stream>>>(bufQ, nullptr, nullptr, out, ROWS);
}

// Round 3
// 484.952 us; speedup vs baseline: 2.1449x; 1.1347x over previous
//
#include <hip/hip_runtime.h>
#include <math.h>

// Problem constants
#define H_    8
#define DH    64
#define NN    512
#define KADJ  16
#define FF    512      // H_*Dh
#define BTOT  24       // B*T
#define ROWS  12288    // B*T*N
#define SN_   27
#define EPS_  1e-5f

typedef short short8 __attribute__((ext_vector_type(8)));
typedef float f32x4  __attribute__((ext_vector_type(4)));

__device__ __forceinline__ ushort f2bf(float x) {
    uint u = __float_as_uint(x);
    u += 0x7FFFu + ((u >> 16) & 1u);
    return (ushort)(u >> 16);
}
__device__ __forceinline__ float bf2f(ushort h) {
    return __uint_as_float(((uint)h) << 16);
}
__device__ __forceinline__ void pack_hilo(float4 a, float4 b, short8& hi, short8& lo) {
    float v[8] = {a.x, a.y, a.z, a.w, b.x, b.y, b.z, b.w};
    #pragma unroll
    for (int j = 0; j < 8; ++j) {
        ushort h = f2bf(v[j]);
        hi[j] = (short)h;
        lo[j] = (short)f2bf(v[j] - bf2f(h));
    }
}

// ---------------------------------------------------------------------------
// Kernel 1: x_ = x + pos, emitted directly as bf16 hi/lo planes
// ---------------------------------------------------------------------------
__global__ __launch_bounds__(256) void add_pos_bf16(
    const float* __restrict__ x,
    const float* __restrict__ spa_val, const float* __restrict__ spa_vec,
    const float* __restrict__ tem_val, const float* __restrict__ tem_vec,
    ushort* __restrict__ xh, ushort* __restrict__ xl)
{
    int i = blockIdx.x * 256 + threadIdx.x;   // float4 index, 1,572,864 total
    int f4  = i & 127;
    int row = i >> 7;
    int n   = row & (NN - 1);

    float4 xv = reinterpret_cast<const float4*>(x)[i];
    float4 sv = reinterpret_cast<const float4*>(spa_vec)[n * 128 + f4];
    float4 tv = reinterpret_cast<const float4*>(tem_vec)[n * 128 + f4];
    float4 se = reinterpret_cast<const float4*>(spa_val)[f4];
    float4 te = reinterpret_cast<const float4*>(tem_val)[f4];
    float r0 = xv.x + sv.x * se.x + tv.x * te.x;
    float r1 = xv.y + sv.y * se.y + tv.y * te.y;
    float r2 = xv.z + sv.z * se.z + tv.z * te.z;
    float r3 = xv.w + sv.w * se.w + tv.w * te.w;
    ushort h0 = f2bf(r0), h1 = f2bf(r1), h2 = f2bf(r2), h3 = f2bf(r3);
    reinterpret_cast<ushort4*>(xh)[i] = make_ushort4(h0, h1, h2, h3);
    reinterpret_cast<ushort4*>(xl)[i] = make_ushort4(
        f2bf(r0 - bf2f(h0)), f2bf(r1 - bf2f(h1)),
        f2bf(r2 - bf2f(h2)), f2bf(r3 - bf2f(h3)));
}

// ---------------------------------------------------------------------------
// Kernel 2: weight pre-convert: 6 weights -> hi planes; lo planes for w0,w1
// ---------------------------------------------------------------------------
__global__ __launch_bounds__(256) void wconv_kernel(
    const float* __restrict__ w0, const float* __restrict__ w1,
    const float* __restrict__ w2, const float* __restrict__ w3,
    const float* __restrict__ w4, const float* __restrict__ w5,
    ushort* __restrict__ whi, ushort* __restrict__ wlo)
{
    const int wi = blockIdx.y;
    const float* W = wi == 0 ? w0 : wi == 1 ? w1 : wi == 2 ? w2 :
                     wi == 3 ? w3 : wi == 4 ? w4 : w5;
    int i = blockIdx.x * 256 + threadIdx.x;   // 0..65535 float4
    float4 v = reinterpret_cast<const float4*>(W)[i];
    ushort h0 = f2bf(v.x), h1 = f2bf(v.y), h2 = f2bf(v.z), h3 = f2bf(v.w);
    reinterpret_cast<ushort4*>(whi + (size_t)wi * 262144)[i] =
        make_ushort4(h0, h1, h2, h3);
    if (wi < 2) {
        reinterpret_cast<ushort4*>(wlo + (size_t)wi * 262144)[i] =
            make_ushort4(f2bf(v.x - bf2f(h0)), f2bf(v.y - bf2f(h1)),
                         f2bf(v.z - bf2f(h2)), f2bf(v.w - bf2f(h3)));
    }
}

// ---------------------------------------------------------------------------
// Kernel 3: MFMA GEMM, bf16 inputs. C = A[M,512] * W[512,512]^T + bias
// SPLIT=1: A,W have lo planes (3 MFMA). EPI: 0 none, 1 relu, 2 +addsrc.
// OUTBF=1: write bf16 to Cb, else fp32 to Cf.
// Tile 128x64x64, 256 threads (4 waves, 2m x 2n).
// ---------------------------------------------------------------------------
#define GBM 128
#define GBN 64
#define GBK 64
#define LDPA 72   // row stride in ushorts (144 B): slot stride 9 mod 8 -> 2-way max

template <int SPLIT, int EPI, int OUTBF>
__global__ __launch_bounds__(256) void gemm_bf16(
    const ushort* __restrict__ Ah, const ushort* __restrict__ Al,
    const ushort* __restrict__ Wh, const ushort* __restrict__ Wl,
    const float* __restrict__ bias, const float* __restrict__ addsrc,
    float* __restrict__ Cf, ushort* __restrict__ Cb)
{
    __shared__ ushort sAh[GBM * LDPA];
    __shared__ ushort sAl[SPLIT ? GBM * LDPA : 8];
    __shared__ ushort sWh[GBN * LDPA];
    __shared__ ushort sWl[SPLIT ? GBN * LDPA : 8];

    const int tid  = threadIdx.x;
    const int lane = tid & 63;
    const int wid  = tid >> 6;
    const int wm   = wid & 1;
    const int wn   = wid >> 1;
    const int rowBase = blockIdx.y * GBM;
    const int colBase = blockIdx.x * GBN;

    const int arow = tid >> 1, ahalf = tid & 1;   // 128 rows, 32-ushort halves
    const int wrow = tid >> 2, wq = tid & 3;      // 64 rows, 16-ushort quarters

    const ushort* aph = Ah + (size_t)(rowBase + arow) * FF + ahalf * 32;
    const ushort* wph = Wh + (size_t)(colBase + wrow) * FF + wq * 16;
    const ushort* apl = SPLIT ? Al + (size_t)(rowBase + arow) * FF + ahalf * 32 : nullptr;
    const ushort* wpl = SPLIT ? Wl + (size_t)(colBase + wrow) * FF + wq * 16 : nullptr;

    uint4 rah[4], ral[4], rwh[2], rwl[2];
    #pragma unroll
    for (int i = 0; i < 4; ++i) rah[i] = ((const uint4*)aph)[i];
    #pragma unroll
    for (int i = 0; i < 2; ++i) rwh[i] = ((const uint4*)wph)[i];
    if (SPLIT) {
        #pragma unroll
        for (int i = 0; i < 4; ++i) ral[i] = ((const uint4*)apl)[i];
        #pragma unroll
        for (int i = 0; i < 2; ++i) rwl[i] = ((const uint4*)wpl)[i];
    }

    f32x4 acc[4][2];
    #pragma unroll
    for (int mi = 0; mi < 4; ++mi)
        #pragma unroll
        for (int ni = 0; ni < 2; ++ni) acc[mi][ni] = (f32x4){0.f, 0.f, 0.f, 0.f};

    const int ai  = arow * LDPA + ahalf * 32;
    const int wi2 = wrow * LDPA + wq * 16;

    for (int step = 0; step < FF / GBK; ++step) {
        #pragma unroll
        for (int i = 0; i < 4; ++i) *(uint4*)&sAh[ai + 8 * i] = rah[i];
        #pragma unroll
        for (int i = 0; i < 2; ++i) *(uint4*)&sWh[wi2 + 8 * i] = rwh[i];
        if (SPLIT) {
            #pragma unroll
            for (int i = 0; i < 4; ++i) *(uint4*)&sAl[ai + 8 * i] = ral[i];
            #pragma unroll
            for (int i = 0; i < 2; ++i) *(uint4*)&sWl[wi2 + 8 * i] = rwl[i];
        }
        __syncthreads();

        if (step < FF / GBK - 1) {
            const int off = (step + 1) * GBK;
            #pragma unroll
            for (int i = 0; i < 4; ++i) rah[i] = ((const uint4*)(aph + off))[i];
            #pragma unroll
            for (int i = 0; i < 2; ++i) rwh[i] = ((const uint4*)(wph + off))[i];
            if (SPLIT) {
                #pragma unroll
                for (int i = 0; i < 4; ++i) ral[i] = ((const uint4*)(apl + off))[i];
                #pragma unroll
                for (int i = 0; i < 2; ++i) rwl[i] = ((const uint4*)(wpl + off))[i];
            }
        }

        #pragma unroll
        for (int ksub = 0; ksub < 2; ++ksub) {
            const int kc = (lane >> 4) * 8 + ksub * 32;
            short8 afh[4], wfh[2], afl[4], wfl[2];
            #pragma unroll
            for (int mi = 0; mi < 4; ++mi) {
                const int r = wm * 64 + mi * 16 + (lane & 15);
                afh[mi] = *(const short8*)&sAh[r * LDPA + kc];
                if (SPLIT) afl[mi] = *(const short8*)&sAl[r * LDPA + kc];
            }
            #pragma unroll
            for (int ni = 0; ni < 2; ++ni) {
                const int r = wn * 32 + ni * 16 + (lane & 15);
                wfh[ni] = *(const short8*)&sWh[r * LDPA + kc];
                if (SPLIT) wfl[ni] = *(const short8*)&sWl[r * LDPA + kc];
            }
            #pragma unroll
            for (int mi = 0; mi < 4; ++mi)
                #pragma unroll
                for (int ni = 0; ni < 2; ++ni) {
                    acc[mi][ni] = __builtin_amdgcn_mfma_f32_16x16x32_bf16(
                        afh[mi], wfh[ni], acc[mi][ni], 0, 0, 0);
                    if (SPLIT) {
                        acc[mi][ni] = __builtin_amdgcn_mfma_f32_16x16x32_bf16(
                            afh[mi], wfl[ni], acc[mi][ni], 0, 0, 0);
                        acc[mi][ni] = __builtin_amdgcn_mfma_f32_16x16x32_bf16(
                            afl[mi], wfh[ni], acc[mi][ni], 0, 0, 0);
                    }
                }
        }
        __syncthreads();
    }

    #pragma unroll
    for (int mi = 0; mi < 4; ++mi)
        #pragma unroll
        for (int ni = 0; ni < 2; ++ni) {
            const int col = colBase + wn * 32 + ni * 16 + (lane & 15);
            const float bcol = bias[col];
            #pragma unroll
            for (int r = 0; r < 4; ++r) {
                const int row = rowBase + wm * 64 + mi * 16 + (lane >> 4) * 4 + r;
                float v = acc[mi][ni][r] + bcol;
                if (EPI == 1) v = fmaxf(v, 0.0f);
                if (EPI == 2) v += addsrc[(size_t)row * FF + col];
                if (OUTBF) Cb[(size_t)row * FF + col] = f2bf(v);
                else       Cf[(size_t)row * FF + col] = v;
            }
        }
}

// ---------------------------------------------------------------------------
// Kernel 4: qks + M, wave per (h,bt,n), lane = d
// ---------------------------------------------------------------------------
__global__ __launch_bounds__(256) void qks_M_kernel(
    const float* __restrict__ Q, const float* __restrict__ K,
    const int* __restrict__ adj, const float* __restrict__ w_proj,
    const float* __restrict__ b_proj, float* __restrict__ Mout)
{
    const int w = blockIdx.x * 4 + (threadIdx.x >> 6);
    const int lane = threadIdx.x & 63;
    const int n   = w & (NN - 1);
    const int hbt = w >> 9;
    const int h   = hbt / BTOT;
    const int bt  = hbt % BTOT;

    float s = 0.0f;
    #pragma unroll
    for (int k = 0; k < KADJ; ++k) {
        const int j = adj[n * KADJ + k];
        s += w_proj[k] * K[((size_t)(bt * NN + j)) * FF + h * DH + lane];
    }
    float t = Q[((size_t)(bt * NN + n)) * FF + h * DH + lane] * s;
    #pragma unroll
    for (int o = 32; o; o >>= 1) t += __shfl_xor(t, o);
    if (lane == 0) Mout[(size_t)hbt * NN + n] = t + b_proj[0];
}

// ---------------------------------------------------------------------------
// Kernel 5: top-27 per group, one wave per group
// ---------------------------------------------------------------------------
__global__ __launch_bounds__(64) void topk_kernel(
    const float* __restrict__ M, int* __restrict__ mtop)
{
    const int g = blockIdx.x;
    __shared__ float vals[NN];
    const int lane = threadIdx.x;
    for (int i = lane; i < NN; i += 64) vals[i] = M[(size_t)g * NN + i];
    __syncthreads();

    for (int s = 0; s < SN_; ++s) {
        float bv = -INFINITY;
        int bi = 1 << 30;
        for (int i = lane; i < NN; i += 64) {
            float v = vals[i];
            if (v > bv || (v == bv && i < bi)) { bv = v; bi = i; }
        }
        #pragma unroll
        for (int o = 32; o; o >>= 1) {
            float ov = __shfl_xor(bv, o);
            int   oi = __shfl_xor(bi, o);
            if (ov > bv || (ov == bv && oi < bi)) { bv = ov; bi = oi; }
        }
        if (lane == 0) {
            mtop[g * SN_ + s] = bi;
            vals[bi] = -INFINITY;
        }
        __syncthreads();
    }
}

// ---------------------------------------------------------------------------
// Kernel 6: fused attention per g = (h,bt). 512 threads = 8 waves.
// scores (split-bf16 MFMA, wave = 64-col slice) -> in-register softmax
// (cross-wave LDS reduce) -> cp argmax in-register -> P bf16 to swizzled LDS
// -> PV MFMA (wave = (m,dtile)) -> scatter rows by cp, bf16 output.
// ---------------------------------------------------------------------------
__global__ __launch_bounds__(512) void fused_attn(
    const float* __restrict__ Q, const float* __restrict__ K,
    const float* __restrict__ V, const int* __restrict__ mtop,
    ushort* __restrict__ attnout)
{
    __shared__ ushort P_lds[32 * 512];    // 32 KB, XOR-swizzled
    __shared__ float red0[8][32];
    __shared__ float red1[8][32];
    __shared__ float val_lds[32][68];
    __shared__ int   cp_lds[NN];
    __shared__ int   mt[32];

    const int g = blockIdx.x;
    const int h = g / BTOT, bt = g % BTOT;
    const int tid = threadIdx.x;
    const int wave = tid >> 6, lane = tid & 63;
    const int q = lane >> 4, c = lane & 15;
    const size_t base_bt = (size_t)bt * NN * FF;
    const int hcol = h * DH;

    if (tid < 32) mt[tid] = mtop[g * SN_ + (tid < SN_ ? tid : 0)];
    __syncthreads();

    // ---- A fragments: Qr rows (via mt), split hi/lo ----
    short8 afh[2][2], afl[2][2];
    #pragma unroll
    for (int m = 0; m < 2; ++m) {
        const int grow = mt[m * 16 + c];
        const float* qp = Q + base_bt + (size_t)grow * FF + hcol + q * 8;
        #pragma unroll
        for (int ks = 0; ks < 2; ++ks) {
            float4 a0 = *(const float4*)(qp + ks * 32);
            float4 a1 = *(const float4*)(qp + ks * 32 + 4);
            pack_hilo(a0, a1, afh[m][ks], afl[m][ks]);
        }
    }

    // ---- B fragments: K rows for this wave's 64-col slice ----
    const int n0 = wave * 64;
    short8 bfh[4][2], bfl[4][2];
    #pragma unroll
    for (int nt = 0; nt < 4; ++nt) {
        const int krow = n0 + nt * 16 + c;
        const float* kp = K + base_bt + (size_t)krow * FF + hcol + q * 8;
        #pragma unroll
        for (int ks = 0; ks < 2; ++ks) {
            float4 b0 = *(const float4*)(kp + ks * 32);
            float4 b1 = *(const float4*)(kp + ks * 32 + 4);
            pack_hilo(b0, b1, bfh[nt][ks], bfl[nt][ks]);
        }
    }

    // ---- scores (split: hh + hl + lh), then scale 1/8 ----
    f32x4 sc[2][4];
    #pragma unroll
    for (int m = 0; m < 2; ++m)
        #pragma unroll
        for (int nt = 0; nt < 4; ++nt) sc[m][nt] = (f32x4){0.f, 0.f, 0.f, 0.f};
    #pragma unroll
    for (int ks = 0; ks < 2; ++ks)
        #pragma unroll
        for (int m = 0; m < 2; ++m)
            #pragma unroll
            for (int nt = 0; nt < 4; ++nt) {
                sc[m][nt] = __builtin_amdgcn_mfma_f32_16x16x32_bf16(
                    afh[m][ks], bfh[nt][ks], sc[m][nt], 0, 0, 0);
                sc[m][nt] = __builtin_amdgcn_mfma_f32_16x16x32_bf16(
                    afh[m][ks], bfl[nt][ks], sc[m][nt], 0, 0, 0);
                sc[m][nt] = __builtin_amdgcn_mfma_f32_16x16x32_bf16(
                    afl[m][ks], bfh[nt][ks], sc[m][nt], 0, 0, 0);
            }
    #pragma unroll
    for (int m = 0; m < 2; ++m)
        #pragma unroll
        for (int nt = 0; nt < 4; ++nt)
            #pragma unroll
            for (int r = 0; r < 4; ++r) sc[m][nt][r] *= 0.125f;

    // ---- row max (rows = m*16 + q*4 + r) ----
    float rmax[2][4];
    #pragma unroll
    for (int m = 0; m < 2; ++m)
        #pragma unroll
        for (int r = 0; r < 4; ++r) {
            float v = sc[m][0][r];
            v = fmaxf(v, sc[m][1][r]);
            v = fmaxf(v, sc[m][2][r]);
            v = fmaxf(v, sc[m][3][r]);
            rmax[m][r] = v;
        }
    #pragma unroll
    for (int off = 1; off <= 8; off <<= 1)
        #pragma unroll
        for (int m = 0; m < 2; ++m)
            #pragma unroll
            for (int r = 0; r < 4; ++r)
                rmax[m][r] = fmaxf(rmax[m][r], __shfl_xor(rmax[m][r], off));
    if (c == 0) {
        #pragma unroll
        for (int m = 0; m < 2; ++m)
            #pragma unroll
            for (int r = 0; r < 4; ++r)
                red0[wave][m * 16 + q * 4 + r] = rmax[m][r];
    }
    __syncthreads();
    float gmax[2][4];
    #pragma unroll
    for (int m = 0; m < 2; ++m)
        #pragma unroll
        for (int r = 0; r < 4; ++r) {
            const int row = m * 16 + q * 4 + r;
            float v = red0[0][row];
            #pragma unroll
            for (int w = 1; w < 8; ++w) v = fmaxf(v, red0[w][row]);
            gmax[m][r] = v;
        }

    // ---- exp + row sum ----
    float rsum[2][4] = {};
    #pragma unroll
    for (int m = 0; m < 2; ++m)
        #pragma unroll
        for (int nt = 0; nt < 4; ++nt)
            #pragma unroll
            for (int r = 0; r < 4; ++r) {
                float e = expf(sc[m][nt][r] - gmax[m][r]);
                sc[m][nt][r] = e;
                rsum[m][r] += e;
            }
    #pragma unroll
    for (int off = 1; off <= 8; off <<= 1)
        #pragma unroll
        for (int m = 0; m < 2; ++m)
            #pragma unroll
            for (int r = 0; r < 4; ++r)
                rsum[m][r] += __shfl_xor(rsum[m][r], off);
    if (c == 0) {
        #pragma unroll
        for (int m = 0; m < 2; ++m)
            #pragma unroll
            for (int r = 0; r < 4; ++r)
                red1[wave][m * 16 + q * 4 + r] = rsum[m][r];
    }
    __syncthreads();
    #pragma unroll
    for (int m = 0; m < 2; ++m)
        #pragma unroll
        for (int r = 0; r < 4; ++r) {
            const int row = m * 16 + q * 4 + r;
            float s = red1[0][row];
            #pragma unroll
            for (int w = 1; w < 8; ++w) s += red1[w][row];
            const float inv = 1.0f / s;
            #pragma unroll
            for (int nt = 0; nt < 4; ++nt) sc[m][nt][r] *= inv;
        }

    // ---- cp argmax over rows < 27, per column ----
    #pragma unroll
    for (int nt = 0; nt < 4; ++nt) {
        float bv = -INFINITY;
        int bi = 1 << 30;
        #pragma unroll
        for (int m = 0; m < 2; ++m)
            #pragma unroll
            for (int r = 0; r < 4; ++r) {
                const int row = m * 16 + q * 4 + r;
                if (row < SN_) {
                    float v = sc[m][nt][r];
                    if (v > bv) { bv = v; bi = row; }
                }
            }
        #pragma unroll
        for (int off = 16; off <= 32; off <<= 1) {
            float ov = __shfl_xor(bv, off);
            int   oi = __shfl_xor(bi, off);
            if (ov > bv || (ov == bv && oi < bi)) { bv = ov; bi = oi; }
        }
        if (q == 0) cp_lds[n0 + nt * 16 + c] = bi;
    }

    // ---- write P (bf16) to swizzled LDS ----
    #pragma unroll
    for (int m = 0; m < 2; ++m)
        #pragma unroll
        for (int nt = 0; nt < 4; ++nt)
            #pragma unroll
            for (int r = 0; r < 4; ++r) {
                const int row = m * 16 + q * 4 + r;
                const int col = n0 + nt * 16 + c;
                P_lds[(row * 512 + col) ^ ((row & 7) << 3)] = f2bf(sc[m][nt][r]);
            }
    __syncthreads();

    // ---- PV: wave = (msel, dtile); k = n in 16 steps of 32 ----
    const int msel = wave >> 2, dt = wave & 3;
    const int dcol = hcol + dt * 16 + c;
    const float* vb = V + base_bt + dcol;
    const int prow = msel * 16 + c;
    const int pswz = (prow & 7) << 3;
    f32x4 acc = (f32x4){0.f, 0.f, 0.f, 0.f};
    for (int kstep = 0; kstep < 16; ++kstep) {
        short8 a = *(const short8*)&P_lds[(prow * 512 + kstep * 32 + q * 8) ^ pswz];
        short8 b;
        #pragma unroll
        for (int j = 0; j < 8; ++j)
            b[j] = (short)f2bf(vb[(size_t)(kstep * 32 + q * 8 + j) * FF]);
        acc = __builtin_amdgcn_mfma_f32_16x16x32_bf16(a, b, acc, 0, 0, 0);
    }
    #pragma unroll
    for (int r = 0; r < 4; ++r)
        val_lds[msel * 16 + q * 4 + r][dt * 16 + c] = acc[r];
    __syncthreads();

    // ---- scatter: attnout[n][hcol+d] = val[cp[n]][d] (bf16) ----
    #pragma unroll
    for (int pass = 0; pass < 8; ++pass) {
        const int n  = pass * 64 + (tid >> 3);
        const int s  = cp_lds[n];
        const int d0 = (tid & 7) * 8;
        const float* vr = &val_lds[s][d0];
        uint4 u;
        u.x = (uint)f2bf(vr[0]) | ((uint)f2bf(vr[1]) << 16);
        u.y = (uint)f2bf(vr[2]) | ((uint)f2bf(vr[3]) << 16);
        u.z = (uint)f2bf(vr[4]) | ((uint)f2bf(vr[5]) << 16);
        u.w = (uint)f2bf(vr[6]) | ((uint)f2bf(vr[7]) << 16);
        *(uint4*)(attnout + base_bt + (size_t)n * FF + hcol + d0) = u;
    }
}

// ---------------------------------------------------------------------------
// Kernel 7: LayerNorm over last dim. BFOUT adds a bf16 copy of the result.
// ---------------------------------------------------------------------------
template <int AFFINE, int BFOUT>
__global__ __launch_bounds__(256) void ln_kernel(
    const float* __restrict__ X, const float* __restrict__ g,
    const float* __restrict__ b, float* __restrict__ Yf,
    ushort* __restrict__ Yb, int rows)
{
    const int row = blockIdx.x * 4 + (threadIdx.x >> 6);
    if (row >= rows) return;
    const int lane = threadIdx.x & 63;
    const float4* x4 = reinterpret_cast<const float4*>(X + (size_t)row * FF);
    float4 a = x4[lane];
    float4 c = x4[lane + 64];
    float s = a.x + a.y + a.z + a.w + c.x + c.y + c.z + c.w;
    float q = a.x * a.x + a.y * a.y + a.z * a.z + a.w * a.w +
              c.x * c.x + c.y * c.y + c.z * c.z + c.w * c.w;
    #pragma unroll
    for (int o = 32; o; o >>= 1) {
        s += __shfl_xor(s, o);
        q += __shfl_xor(q, o);
    }
    const float mu   = s * (1.0f / FF);
    const float var  = q * (1.0f / FF) - mu * mu;
    const float rstd = 1.0f / sqrtf(var + EPS_);

    float4 ya, yc;
    ya.x = (a.x - mu) * rstd; ya.y = (a.y - mu) * rstd;
    ya.z = (a.z - mu) * rstd; ya.w = (a.w - mu) * rstd;
    yc.x = (c.x - mu) * rstd; yc.y = (c.y - mu) * rstd;
    yc.z = (c.z - mu) * rstd; yc.w = (c.w - mu) * rstd;
    if (AFFINE) {
        float4 ga = reinterpret_cast<const float4*>(g)[lane];
        float4 gc = reinterpret_cast<const float4*>(g)[lane + 64];
        float4 ba = reinterpret_cast<const float4*>(b)[lane];
        float4 bc = reinterpret_cast<const float4*>(b)[lane + 64];
        ya.x = ya.x * ga.x + ba.x; ya.y = ya.y * ga.y + ba.y;
        ya.z = ya.z * ga.z + ba.z; ya.w = ya.w * ga.w + ba.w;
        yc.x = yc.x * gc.x + bc.x; yc.y = yc.y * gc.y + bc.y;
        yc.z = yc.z * gc.z + bc.z; yc.w = yc.w * gc.w + bc.w;
    }
    float4* y4 = reinterpret_cast<float4*>(Yf + (size_t)row * FF);
    y4[lane]      = ya;
    y4[lane + 64] = yc;
    if (BFOUT) {
        ushort4* yb = reinterpret_cast<ushort4*>(Yb + (size_t)row * FF);
        yb[lane] = make_ushort4(f2bf(ya.x), f2bf(ya.y), f2bf(ya.z), f2bf(ya.w));
        yb[lane + 64] = make_ushort4(f2bf(yc.x), f2bf(yc.y), f2bf(yc.z), f2bf(yc.w));
    }
}

// ---------------------------------------------------------------------------
// Launch
// ---------------------------------------------------------------------------
extern "C" void kernel_launch(void* const* d_in, const int* in_sizes, int n_in,
                              void* d_out, int out_size, void* d_ws, size_t ws_size,
                              hipStream_t stream)
{
    const float* x       = (const float*)d_in[0];
    const float* spa_val = (const float*)d_in[1];
    const float* spa_vec = (const float*)d_in[2];
    const float* tem_val = (const float*)d_in[3];
    const float* tem_vec = (const float*)d_in[4];
    const int*   adj     = (const int*)  d_in[5];
    const float* Wq = (const float*)d_in[6];  const float* bq = (const float*)d_in[7];
    const float* Wk = (const float*)d_in[8];  const float* bk = (const float*)d_in[9];
    const float* Wv = (const float*)d_in[10]; const float* bv = (const float*)d_in[11];
    const float* Wo = (const float*)d_in[12]; const float* bo = (const float*)d_in[13];
    const float* w_proj = (const float*)d_in[14];
    const float* b_proj = (const float*)d_in[15];
    const float* gamma  = (const float*)d_in[16];
    const float* beta   = (const float*)d_in[17];
    const float* W1 = (const float*)d_in[18]; const float* b1 = (const float*)d_in[19];
    const float* W2 = (const float*)d_in[20]; const float* b2 = (const float*)d_in[21];

    float* out = (float*)d_out;
    float* ws  = (float*)d_ws;

    const size_t R = (size_t)ROWS * FF;   // 6,291,456

    // ws layout (floats)
    float* bufQ = ws;
    float* bufK = ws + R;
    float* bufV = ws + 2 * R;
    ushort* whi = (ushort*)(ws + 3 * R);           // 6 * 262144 ushorts
    ushort* wlo = whi + 6 * 262144;                // 2 * 262144 ushorts (wq, wk)
    float* Mbuf = ws + 3 * R + (6 * 262144 + 2 * 262144) / 2;   // 98,304 floats
    int*   mtop = (int*)(Mbuf + (size_t)H_ * BTOT * NN);        // 5,184 ints

    // d_out scratch timeline: [xh|xl] -> [attnout|vbf16] -> [h1b|..] -> final
    ushort* xh  = (ushort*)d_out;
    ushort* xl  = xh + R;
    ushort* attnout = xh;        // after x_ dead
    ushort* vbf = xl;            // second half
    ushort* h1b = xh;            // first half (attnout dead after Wo gemm)

    // 1. x_ -> bf16 hi/lo planes
    add_pos_bf16<<<(ROWS * FF / 4) / 256, 256, 0, stream>>>(
        x, spa_val, spa_vec, tem_val, tem_vec, xh, xl);

    // 2. weight pre-convert
    wconv_kernel<<<dim3(256, 6), 256, 0, stream>>>(Wq, Wk, Wv, Wo, W1, W2, whi, wlo);

    // 3. Q/K/V projections
    dim3 gg(FF / GBN, ROWS / GBM);   // (8, 96)
    gemm_bf16<1, 0, 0><<<gg, 256, 0, stream>>>(xh, xl, whi, wlo, bq, nullptr, bufQ, nullptr);
    gemm_bf16<1, 0, 0><<<gg, 256, 0, stream>>>(xh, xl, whi + 262144, wlo + 262144, bk, nullptr, bufK, nullptr);
    gemm_bf16<0, 0, 0><<<gg, 256, 0, stream>>>(xh, nullptr, whi + 2 * 262144, nullptr, bv, nullptr, bufV, nullptr);

    // 4. M scores + top-27
    qks_M_kernel<<<(H_ * BTOT * NN) / 4, 256, 0, stream>>>(
        bufQ, bufK, adj, w_proj, b_proj, Mbuf);
    topk_kernel<<<H_ * BTOT, 64, 0, stream>>>(Mbuf, mtop);

    // 5. fused attention -> attnout (bf16)
    fused_attn<<<H_ * BTOT, 512, 0, stream>>>(bufQ, bufK, bufV, mtop, attnout);

    // 6. output projection + LN + FFN
    gemm_bf16<0, 0, 0><<<gg, 256, 0, stream>>>(attnout, nullptr, whi + 3 * 262144, nullptr, bo, nullptr, bufQ, nullptr);
    ln_kernel<1, 1><<<ROWS / 4, 256, 0, stream>>>(bufQ, gamma, beta, bufK, vbf, ROWS);
    gemm_bf16<0, 1, 1><<<gg, 256, 0, stream>>>(vbf, nullptr, whi + 4 * 262144, nullptr, b1, nullptr, nullptr, h1b);
    gemm_bf16<0, 2, 0><<<gg, 256, 0, stream>>>(h1b, nullptr, whi + 5 * 262144, nullptr, b2, bufK, bufV, nullptr);
    ln_kernel<0, 0><<<ROWS / 4, 256, 0, stream>>>(bufV, nullptr, nullptr, out, nullptr, ROWS);
}

// Round 4
// 236.629 us; speedup vs baseline: 4.3957x; 2.0494x over previous
//
#include <hip/hip_runtime.h>
#include <math.h>

// Problem constants
#define H_    8
#define DH    64
#define NN    512
#define KADJ  16
#define FF    512      // H_*Dh
#define BTOT  24       // B*T
#define ROWS  12288    // B*T*N
#define SN_   27
#define EPS_  1e-5f

typedef short short8 __attribute__((ext_vector_type(8)));
typedef float f32x4  __attribute__((ext_vector_type(4)));

__device__ __forceinline__ ushort f2bf(float x) {
    uint u = __float_as_uint(x);
    u += 0x7FFFu + ((u >> 16) & 1u);
    return (ushort)(u >> 16);
}
__device__ __forceinline__ float bf2f(ushort h) {
    return __uint_as_float(((uint)h) << 16);
}
__device__ __forceinline__ void pack_hilo(float4 a, float4 b, short8& hi, short8& lo) {
    float v[8] = {a.x, a.y, a.z, a.w, b.x, b.y, b.z, b.w};
    #pragma unroll
    for (int j = 0; j < 8; ++j) {
        ushort h = f2bf(v[j]);
        hi[j] = (short)h;
        lo[j] = (short)f2bf(v[j] - bf2f(h));
    }
}

// async global->LDS, 16B per lane; LDS dest = wave-uniform base + lane*16
__device__ __forceinline__ void gload_lds16(const ushort* g, ushort* l) {
    __builtin_amdgcn_global_load_lds(
        (const __attribute__((address_space(1))) unsigned int*)g,
        (__attribute__((address_space(3))) unsigned int*)l,
        16, 0, 0);
}

// ---------------------------------------------------------------------------
// Kernel 1: x_ = x + pos, emitted directly as bf16 hi/lo planes
// ---------------------------------------------------------------------------
__global__ __launch_bounds__(256) void add_pos_bf16(
    const float* __restrict__ x,
    const float* __restrict__ spa_val, const float* __restrict__ spa_vec,
    const float* __restrict__ tem_val, const float* __restrict__ tem_vec,
    ushort* __restrict__ xh, ushort* __restrict__ xl)
{
    int i = blockIdx.x * 256 + threadIdx.x;   // float4 index, 1,572,864 total
    int f4  = i & 127;
    int row = i >> 7;
    int n   = row & (NN - 1);

    float4 xv = reinterpret_cast<const float4*>(x)[i];
    float4 sv = reinterpret_cast<const float4*>(spa_vec)[n * 128 + f4];
    float4 tv = reinterpret_cast<const float4*>(tem_vec)[n * 128 + f4];
    float4 se = reinterpret_cast<const float4*>(spa_val)[f4];
    float4 te = reinterpret_cast<const float4*>(tem_val)[f4];
    float r0 = xv.x + sv.x * se.x + tv.x * te.x;
    float r1 = xv.y + sv.y * se.y + tv.y * te.y;
    float r2 = xv.z + sv.z * se.z + tv.z * te.z;
    float r3 = xv.w + sv.w * se.w + tv.w * te.w;
    ushort h0 = f2bf(r0), h1 = f2bf(r1), h2 = f2bf(r2), h3 = f2bf(r3);
    reinterpret_cast<ushort4*>(xh)[i] = make_ushort4(h0, h1, h2, h3);
    reinterpret_cast<ushort4*>(xl)[i] = make_ushort4(
        f2bf(r0 - bf2f(h0)), f2bf(r1 - bf2f(h1)),
        f2bf(r2 - bf2f(h2)), f2bf(r3 - bf2f(h3)));
}

// ---------------------------------------------------------------------------
// Kernel 2: weight pre-convert: 6 weights -> hi planes; lo planes for w0,w1
// ---------------------------------------------------------------------------
__global__ __launch_bounds__(256) void wconv_kernel(
    const float* __restrict__ w0, const float* __restrict__ w1,
    const float* __restrict__ w2, const float* __restrict__ w3,
    const float* __restrict__ w4, const float* __restrict__ w5,
    ushort* __restrict__ whi, ushort* __restrict__ wlo)
{
    const int wi = blockIdx.y;
    const float* W = wi == 0 ? w0 : wi == 1 ? w1 : wi == 2 ? w2 :
                     wi == 3 ? w3 : wi == 4 ? w4 : w5;
    int i = blockIdx.x * 256 + threadIdx.x;   // 0..65535 float4
    float4 v = reinterpret_cast<const float4*>(W)[i];
    ushort h0 = f2bf(v.x), h1 = f2bf(v.y), h2 = f2bf(v.z), h3 = f2bf(v.w);
    reinterpret_cast<ushort4*>(whi + (size_t)wi * 262144)[i] =
        make_ushort4(h0, h1, h2, h3);
    if (wi < 2) {
        reinterpret_cast<ushort4*>(wlo + (size_t)wi * 262144)[i] =
            make_ushort4(f2bf(v.x - bf2f(h0)), f2bf(v.y - bf2f(h1)),
                         f2bf(v.z - bf2f(h2)), f2bf(v.w - bf2f(h3)));
    }
}

// ---------------------------------------------------------------------------
// Kernel 3: MFMA GEMM, m97 structure. C = A[M,512] * W[512,512]^T + bias
// Tile 64(M) x 128(N) x 64(K). 256 threads, 4 waves (2m x 2n), wave 32x64.
// global_load_lds staging, linear LDS dest + XOR-swizzled source; ds_read
// applies the same swizzle: slot ^= (row&7)  ->  2-way max (free).
// SPLIT=1: hi/lo planes interleaved in slots 0-3/4-7 of each 128B LDS row,
//          BK=32, 16 steps, 3 MFMA (hh+hl+lh) per fragment pair.
// EPI: 0 none, 1 relu, 2 +addsrc.  OUTBF: bf16 output to Cb else fp32 to Cf.
// Grid: 768 blocks (192 row-tiles x 4 col-tiles), XCD-swizzled.
// ---------------------------------------------------------------------------
#define GBM 64
#define GBN 128

template <int SPLIT, int EPI, int OUTBF>
__global__ __launch_bounds__(256, 2) void gemm_mfma2(
    const ushort* __restrict__ Ah, const ushort* __restrict__ Al,
    const ushort* __restrict__ Wh, const ushort* __restrict__ Wl,
    const float* __restrict__ bias, const float* __restrict__ addsrc,
    float* __restrict__ Cf, ushort* __restrict__ Cb)
{
    __shared__ ushort sA[GBM * 64];   //  8 KB
    __shared__ ushort sB[GBN * 64];   // 16 KB

    // XCD-aware bijective swizzle (768 % 8 == 0): each XCD owns 96
    // consecutive logical tiles = 24 row-panels x 4 col-tiles -> A panel and
    // W stay L2-resident per XCD.
    const int nx  = gridDim.x >> 3;
    const int bid = blockIdx.x;
    const int lt  = (bid & 7) * nx + (bid >> 3);
    const int rowBase = (lt >> 2) * GBM;
    const int colBase = (lt & 3) * GBN;

    const int tid  = threadIdx.x;
    const int lane = tid & 63;
    const int wid  = tid >> 6;
    const int q    = lane >> 4;     // 0..3
    const int fr   = lane & 15;
    const int wm   = wid & 1;       // row half (32)
    const int wn   = wid >> 1;      // col half (64)

    // staging source pointers (pre-swizzled): LDS byte p -> row=p>>7,
    // slot=(p>>4)&7, srcslot = slot ^ (row&7)
    const int kadv = SPLIT ? 32 : 64;
    const ushort* asrc[2];
    const ushort* bsrc[4];
    #pragma unroll
    for (int c = 0; c < 2; ++c) {   // A tile: 8KB, wave covers 2KB
        const int p   = wid * 2048 + c * 1024 + lane * 16;
        const int row = p >> 7;
        const int ss  = ((p >> 4) & 7) ^ (row & 7);
        if (!SPLIT)
            asrc[c] = Ah + (size_t)(rowBase + row) * FF + ss * 8;
        else
            asrc[c] = (ss < 4)
                ? Ah + (size_t)(rowBase + row) * FF + ss * 8
                : Al + (size_t)(rowBase + row) * FF + (ss - 4) * 8;
    }
    #pragma unroll
    for (int c = 0; c < 4; ++c) {   // B tile: 16KB, wave covers 4KB
        const int p   = wid * 4096 + c * 1024 + lane * 16;
        const int row = p >> 7;
        const int ss  = ((p >> 4) & 7) ^ (row & 7);
        if (!SPLIT)
            bsrc[c] = Wh + (size_t)(colBase + row) * FF + ss * 8;
        else
            bsrc[c] = (ss < 4)
                ? Wh + (size_t)(colBase + row) * FF + ss * 8
                : Wl + (size_t)(colBase + row) * FF + (ss - 4) * 8;
    }

    f32x4 acc[2][4];
    #pragma unroll
    for (int mi = 0; mi < 2; ++mi)
        #pragma unroll
        for (int ni = 0; ni < 4; ++ni) acc[mi][ni] = (f32x4){0.f, 0.f, 0.f, 0.f};

    const int NSTEP = SPLIT ? 16 : 8;
    const int swz = fr & 7;

    for (int step = 0; step < NSTEP; ++step) {
        #pragma unroll
        for (int c = 0; c < 2; ++c) {
            gload_lds16(asrc[c], &sA[wid * 1024 + c * 512]);
            asrc[c] += kadv;
        }
        #pragma unroll
        for (int c = 0; c < 4; ++c) {
            gload_lds16(bsrc[c], &sB[wid * 2048 + c * 512]);
            bsrc[c] += kadv;
        }
        __syncthreads();   // drains vmcnt -> staged tile visible

        if (!SPLIT) {
            #pragma unroll
            for (int ksub = 0; ksub < 2; ++ksub) {
                const int kq = ksub * 4 + q;
                short8 af[2], bf[4];
                #pragma unroll
                for (int mi = 0; mi < 2; ++mi)
                    af[mi] = *(const short8*)&sA[(wm * 32 + mi * 16 + fr) * 64 +
                                                 ((kq ^ swz) << 3)];
                #pragma unroll
                for (int ni = 0; ni < 4; ++ni)
                    bf[ni] = *(const short8*)&sB[(wn * 64 + ni * 16 + fr) * 64 +
                                                 ((kq ^ swz) << 3)];
                #pragma unroll
                for (int mi = 0; mi < 2; ++mi)
                    #pragma unroll
                    for (int ni = 0; ni < 4; ++ni)
                        acc[mi][ni] = __builtin_amdgcn_mfma_f32_16x16x32_bf16(
                            af[mi], bf[ni], acc[mi][ni], 0, 0, 0);
            }
        } else {
            short8 ah[2], bh[4], t[4];
            #pragma unroll
            for (int mi = 0; mi < 2; ++mi)
                ah[mi] = *(const short8*)&sA[(wm * 32 + mi * 16 + fr) * 64 +
                                             ((q ^ swz) << 3)];
            #pragma unroll
            for (int ni = 0; ni < 4; ++ni)
                bh[ni] = *(const short8*)&sB[(wn * 64 + ni * 16 + fr) * 64 +
                                             ((q ^ swz) << 3)];
            // hh
            #pragma unroll
            for (int mi = 0; mi < 2; ++mi)
                #pragma unroll
                for (int ni = 0; ni < 4; ++ni)
                    acc[mi][ni] = __builtin_amdgcn_mfma_f32_16x16x32_bf16(
                        ah[mi], bh[ni], acc[mi][ni], 0, 0, 0);
            // hl
            #pragma unroll
            for (int ni = 0; ni < 4; ++ni)
                t[ni] = *(const short8*)&sB[(wn * 64 + ni * 16 + fr) * 64 +
                                            (((q + 4) ^ swz) << 3)];
            #pragma unroll
            for (int mi = 0; mi < 2; ++mi)
                #pragma unroll
                for (int ni = 0; ni < 4; ++ni)
                    acc[mi][ni] = __builtin_amdgcn_mfma_f32_16x16x32_bf16(
                        ah[mi], t[ni], acc[mi][ni], 0, 0, 0);
            // lh
            #pragma unroll
            for (int mi = 0; mi < 2; ++mi)
                t[mi] = *(const short8*)&sA[(wm * 32 + mi * 16 + fr) * 64 +
                                            (((q + 4) ^ swz) << 3)];
            #pragma unroll
            for (int mi = 0; mi < 2; ++mi)
                #pragma unroll
                for (int ni = 0; ni < 4; ++ni)
                    acc[mi][ni] = __builtin_amdgcn_mfma_f32_16x16x32_bf16(
                        t[mi], bh[ni], acc[mi][ni], 0, 0, 0);
        }
        __syncthreads();   // all reads done before next stage overwrites
    }

    // epilogue: C/D layout col=lane&15, row=(lane>>4)*4+reg
    #pragma unroll
    for (int mi = 0; mi < 2; ++mi)
        #pragma unroll
        for (int ni = 0; ni < 4; ++ni) {
            const int col = colBase + wn * 64 + ni * 16 + fr;
            const float bcol = bias[col];
            #pragma unroll
            for (int r = 0; r < 4; ++r) {
                const int row = rowBase + wm * 32 + mi * 16 + q * 4 + r;
                float v = acc[mi][ni][r] + bcol;
                if (EPI == 1) v = fmaxf(v, 0.0f);
                if (EPI == 2) v += addsrc[(size_t)row * FF + col];
                if (OUTBF) Cb[(size_t)row * FF + col] = f2bf(v);
                else       Cf[(size_t)row * FF + col] = v;
            }
        }
}

// ---------------------------------------------------------------------------
// Kernel 4: qks + M, wave per (h,bt,n), lane = d
// ---------------------------------------------------------------------------
__global__ __launch_bounds__(256) void qks_M_kernel(
    const float* __restrict__ Q, const float* __restrict__ K,
    const int* __restrict__ adj, const float* __restrict__ w_proj,
    const float* __restrict__ b_proj, float* __restrict__ Mout)
{
    const int w = blockIdx.x * 4 + (threadIdx.x >> 6);
    const int lane = threadIdx.x & 63;
    const int n   = w & (NN - 1);
    const int hbt = w >> 9;
    const int h   = hbt / BTOT;
    const int bt  = hbt % BTOT;

    float s = 0.0f;
    #pragma unroll
    for (int k = 0; k < KADJ; ++k) {
        const int j = adj[n * KADJ + k];
        s += w_proj[k] * K[((size_t)(bt * NN + j)) * FF + h * DH + lane];
    }
    float t = Q[((size_t)(bt * NN + n)) * FF + h * DH + lane] * s;
    #pragma unroll
    for (int o = 32; o; o >>= 1) t += __shfl_xor(t, o);
    if (lane == 0) Mout[(size_t)hbt * NN + n] = t + b_proj[0];
}

// ---------------------------------------------------------------------------
// Kernel 5: top-27 per group, one wave per group
// ---------------------------------------------------------------------------
__global__ __launch_bounds__(64) void topk_kernel(
    const float* __restrict__ M, int* __restrict__ mtop)
{
    const int g = blockIdx.x;
    __shared__ float vals[NN];
    const int lane = threadIdx.x;
    for (int i = lane; i < NN; i += 64) vals[i] = M[(size_t)g * NN + i];
    __syncthreads();

    for (int s = 0; s < SN_; ++s) {
        float bv = -INFINITY;
        int bi = 1 << 30;
        for (int i = lane; i < NN; i += 64) {
            float v = vals[i];
            if (v > bv || (v == bv && i < bi)) { bv = v; bi = i; }
        }
        #pragma unroll
        for (int o = 32; o; o >>= 1) {
            float ov = __shfl_xor(bv, o);
            int   oi = __shfl_xor(bi, o);
            if (ov > bv || (ov == bv && oi < bi)) { bv = ov; bi = oi; }
        }
        if (lane == 0) {
            mtop[g * SN_ + s] = bi;
            vals[bi] = -INFINITY;
        }
        __syncthreads();
    }
}

// ---------------------------------------------------------------------------
// Kernel 6: fused attention per g = (h,bt). 512 threads = 8 waves.
// ---------------------------------------------------------------------------
__global__ __launch_bounds__(512) void fused_attn(
    const float* __restrict__ Q, const float* __restrict__ K,
    const float* __restrict__ V, const int* __restrict__ mtop,
    ushort* __restrict__ attnout)
{
    __shared__ ushort P_lds[32 * 512];    // 32 KB, XOR-swizzled
    __shared__ float red0[8][32];
    __shared__ float red1[8][32];
    __shared__ float val_lds[32][68];
    __shared__ int   cp_lds[NN];
    __shared__ int   mt[32];

    const int g = blockIdx.x;
    const int h = g / BTOT, bt = g % BTOT;
    const int tid = threadIdx.x;
    const int wave = tid >> 6, lane = tid & 63;
    const int q = lane >> 4, c = lane & 15;
    const size_t base_bt = (size_t)bt * NN * FF;
    const int hcol = h * DH;

    if (tid < 32) mt[tid] = mtop[g * SN_ + (tid < SN_ ? tid : 0)];
    __syncthreads();

    // ---- A fragments: Qr rows (via mt), split hi/lo ----
    short8 afh[2][2], afl[2][2];
    #pragma unroll
    for (int m = 0; m < 2; ++m) {
        const int grow = mt[m * 16 + c];
        const float* qp = Q + base_bt + (size_t)grow * FF + hcol + q * 8;
        #pragma unroll
        for (int ks = 0; ks < 2; ++ks) {
            float4 a0 = *(const float4*)(qp + ks * 32);
            float4 a1 = *(const float4*)(qp + ks * 32 + 4);
            pack_hilo(a0, a1, afh[m][ks], afl[m][ks]);
        }
    }

    // ---- B fragments: K rows for this wave's 64-col slice ----
    const int n0 = wave * 64;
    short8 bfh[4][2], bfl[4][2];
    #pragma unroll
    for (int nt = 0; nt < 4; ++nt) {
        const int krow = n0 + nt * 16 + c;
        const float* kp = K + base_bt + (size_t)krow * FF + hcol + q * 8;
        #pragma unroll
        for (int ks = 0; ks < 2; ++ks) {
            float4 b0 = *(const float4*)(kp + ks * 32);
            float4 b1 = *(const float4*)(kp + ks * 32 + 4);
            pack_hilo(b0, b1, bfh[nt][ks], bfl[nt][ks]);
        }
    }

    // ---- scores (split: hh + hl + lh), then scale 1/8 ----
    f32x4 sc[2][4];
    #pragma unroll
    for (int m = 0; m < 2; ++m)
        #pragma unroll
        for (int nt = 0; nt < 4; ++nt) sc[m][nt] = (f32x4){0.f, 0.f, 0.f, 0.f};
    #pragma unroll
    for (int ks = 0; ks < 2; ++ks)
        #pragma unroll
        for (int m = 0; m < 2; ++m)
            #pragma unroll
            for (int nt = 0; nt < 4; ++nt) {
                sc[m][nt] = __builtin_amdgcn_mfma_f32_16x16x32_bf16(
                    afh[m][ks], bfh[nt][ks], sc[m][nt], 0, 0, 0);
                sc[m][nt] = __builtin_amdgcn_mfma_f32_16x16x32_bf16(
                    afh[m][ks], bfl[nt][ks], sc[m][nt], 0, 0, 0);
                sc[m][nt] = __builtin_amdgcn_mfma_f32_16x16x32_bf16(
                    afl[m][ks], bfh[nt][ks], sc[m][nt], 0, 0, 0);
            }
    #pragma unroll
    for (int m = 0; m < 2; ++m)
        #pragma unroll
        for (int nt = 0; nt < 4; ++nt)
            #pragma unroll
            for (int r = 0; r < 4; ++r) sc[m][nt][r] *= 0.125f;

    // ---- row max (rows = m*16 + q*4 + r) ----
    float rmax[2][4];
    #pragma unroll
    for (int m = 0; m < 2; ++m)
        #pragma unroll
        for (int r = 0; r < 4; ++r) {
            float v = sc[m][0][r];
            v = fmaxf(v, sc[m][1][r]);
            v = fmaxf(v, sc[m][2][r]);
            v = fmaxf(v, sc[m][3][r]);
            rmax[m][r] = v;
        }
    #pragma unroll
    for (int off = 1; off <= 8; off <<= 1)
        #pragma unroll
        for (int m = 0; m < 2; ++m)
            #pragma unroll
            for (int r = 0; r < 4; ++r)
                rmax[m][r] = fmaxf(rmax[m][r], __shfl_xor(rmax[m][r], off));
    if (c == 0) {
        #pragma unroll
        for (int m = 0; m < 2; ++m)
            #pragma unroll
            for (int r = 0; r < 4; ++r)
                red0[wave][m * 16 + q * 4 + r] = rmax[m][r];
    }
    __syncthreads();
    float gmax[2][4];
    #pragma unroll
    for (int m = 0; m < 2; ++m)
        #pragma unroll
        for (int r = 0; r < 4; ++r) {
            const int row = m * 16 + q * 4 + r;
            float v = red0[0][row];
            #pragma unroll
            for (int w = 1; w < 8; ++w) v = fmaxf(v, red0[w][row]);
            gmax[m][r] = v;
        }

    // ---- exp + row sum ----
    float rsum[2][4] = {};
    #pragma unroll
    for (int m = 0; m < 2; ++m)
        #pragma unroll
        for (int nt = 0; nt < 4; ++nt)
            #pragma unroll
            for (int r = 0; r < 4; ++r) {
                float e = expf(sc[m][nt][r] - gmax[m][r]);
                sc[m][nt][r] = e;
                rsum[m][r] += e;
            }
    #pragma unroll
    for (int off = 1; off <= 8; off <<= 1)
        #pragma unroll
        for (int m = 0; m < 2; ++m)
            #pragma unroll
            for (int r = 0; r < 4; ++r)
                rsum[m][r] += __shfl_xor(rsum[m][r], off);
    if (c == 0) {
        #pragma unroll
        for (int m = 0; m < 2; ++m)
            #pragma unroll
            for (int r = 0; r < 4; ++r)
                red1[wave][m * 16 + q * 4 + r] = rsum[m][r];
    }
    __syncthreads();
    #pragma unroll
    for (int m = 0; m < 2; ++m)
        #pragma unroll
        for (int r = 0; r < 4; ++r) {
            const int row = m * 16 + q * 4 + r;
            float s = red1[0][row];
            #pragma unroll
            for (int w = 1; w < 8; ++w) s += red1[w][row];
            const float inv = 1.0f / s;
            #pragma unroll
            for (int nt = 0; nt < 4; ++nt) sc[m][nt][r] *= inv;
        }

    // ---- cp argmax over rows < 27, per column ----
    #pragma unroll
    for (int nt = 0; nt < 4; ++nt) {
        float bv = -INFINITY;
        int bi = 1 << 30;
        #pragma unroll
        for (int m = 0; m < 2; ++m)
            #pragma unroll
            for (int r = 0; r < 4; ++r) {
                const int row = m * 16 + q * 4 + r;
                if (row < SN_) {
                    float v = sc[m][nt][r];
                    if (v > bv) { bv = v; bi = row; }
                }
            }
        #pragma unroll
        for (int off = 16; off <= 32; off <<= 1) {
            float ov = __shfl_xor(bv, off);
            int   oi = __shfl_xor(bi, off);
            if (ov > bv || (ov == bv && oi < bi)) { bv = ov; bi = oi; }
        }
        if (q == 0) cp_lds[n0 + nt * 16 + c] = bi;
    }

    // ---- write P (bf16) to swizzled LDS ----
    #pragma unroll
    for (int m = 0; m < 2; ++m)
        #pragma unroll
        for (int nt = 0; nt < 4; ++nt)
            #pragma unroll
            for (int r = 0; r < 4; ++r) {
                const int row = m * 16 + q * 4 + r;
                const int col = n0 + nt * 16 + c;
                P_lds[(row * 512 + col) ^ ((row & 7) << 3)] = f2bf(sc[m][nt][r]);
            }
    __syncthreads();

    // ---- PV: wave = (msel, dtile); k = n in 16 steps of 32 ----
    const int msel = wave >> 2, dt = wave & 3;
    const int dcol = hcol + dt * 16 + c;
    const float* vb = V + base_bt + dcol;
    const int prow = msel * 16 + c;
    const int pswz = (prow & 7) << 3;
    f32x4 acc = (f32x4){0.f, 0.f, 0.f, 0.f};
    for (int kstep = 0; kstep < 16; ++kstep) {
        short8 a = *(const short8*)&P_lds[(prow * 512 + kstep * 32 + q * 8) ^ pswz];
        short8 b;
        #pragma unroll
        for (int j = 0; j < 8; ++j)
            b[j] = (short)f2bf(vb[(size_t)(kstep * 32 + q * 8 + j) * FF]);
        acc = __builtin_amdgcn_mfma_f32_16x16x32_bf16(a, b, acc, 0, 0, 0);
    }
    #pragma unroll
    for (int r = 0; r < 4; ++r)
        val_lds[msel * 16 + q * 4 + r][dt * 16 + c] = acc[r];
    __syncthreads();

    // ---- scatter: attnout[n][hcol+d] = val[cp[n]][d] (bf16) ----
    #pragma unroll
    for (int pass = 0; pass < 8; ++pass) {
        const int n  = pass * 64 + (tid >> 3);
        const int s  = cp_lds[n];
        const int d0 = (tid & 7) * 8;
        const float* vr = &val_lds[s][d0];
        uint4 u;
        u.x = (uint)f2bf(vr[0]) | ((uint)f2bf(vr[1]) << 16);
        u.y = (uint)f2bf(vr[2]) | ((uint)f2bf(vr[3]) << 16);
        u.z = (uint)f2bf(vr[4]) | ((uint)f2bf(vr[5]) << 16);
        u.w = (uint)f2bf(vr[6]) | ((uint)f2bf(vr[7]) << 16);
        *(uint4*)(attnout + base_bt + (size_t)n * FF + hcol + d0) = u;
    }
}

// ---------------------------------------------------------------------------
// Kernel 7: LayerNorm over last dim. BFOUT adds a bf16 copy of the result.
// ---------------------------------------------------------------------------
template <int AFFINE, int BFOUT>
__global__ __launch_bounds__(256) void ln_kernel(
    const float* __restrict__ X, const float* __restrict__ g,
    const float* __restrict__ b, float* __restrict__ Yf,
    ushort* __restrict__ Yb, int rows)
{
    const int row = blockIdx.x * 4 + (threadIdx.x >> 6);
    if (row >= rows) return;
    const int lane = threadIdx.x & 63;
    const float4* x4 = reinterpret_cast<const float4*>(X + (size_t)row * FF);
    float4 a = x4[lane];
    float4 c = x4[lane + 64];
    float s = a.x + a.y + a.z + a.w + c.x + c.y + c.z + c.w;
    float q = a.x * a.x + a.y * a.y + a.z * a.z + a.w * a.w +
              c.x * c.x + c.y * c.y + c.z * c.z + c.w * c.w;
    #pragma unroll
    for (int o = 32; o; o >>= 1) {
        s += __shfl_xor(s, o);
        q += __shfl_xor(q, o);
    }
    const float mu   = s * (1.0f / FF);
    const float var  = q * (1.0f / FF) - mu * mu;
    const float rstd = 1.0f / sqrtf(var + EPS_);

    float4 ya, yc;
    ya.x = (a.x - mu) * rstd; ya.y = (a.y - mu) * rstd;
    ya.z = (a.z - mu) * rstd; ya.w = (a.w - mu) * rstd;
    yc.x = (c.x - mu) * rstd; yc.y = (c.y - mu) * rstd;
    yc.z = (c.z - mu) * rstd; yc.w = (c.w - mu) * rstd;
    if (AFFINE) {
        float4 ga = reinterpret_cast<const float4*>(g)[lane];
        float4 gc = reinterpret_cast<const float4*>(g)[lane + 64];
        float4 ba = reinterpret_cast<const float4*>(b)[lane];
        float4 bc = reinterpret_cast<const float4*>(b)[lane + 64];
        ya.x = ya.x * ga.x + ba.x; ya.y = ya.y * ga.y + ba.y;
        ya.z = ya.z * ga.z + ba.z; ya.w = ya.w * ga.w + ba.w;
        yc.x = yc.x * gc.x + bc.x; yc.y = yc.y * gc.y + bc.y;
        yc.z = yc.z * gc.z + bc.z; yc.w = yc.w * gc.w + bc.w;
    }
    float4* y4 = reinterpret_cast<float4*>(Yf + (size_t)row * FF);
    y4[lane]      = ya;
    y4[lane + 64] = yc;
    if (BFOUT) {
        ushort4* yb = reinterpret_cast<ushort4*>(Yb + (size_t)row * FF);
        yb[lane] = make_ushort4(f2bf(ya.x), f2bf(ya.y), f2bf(ya.z), f2bf(ya.w));
        yb[lane + 64] = make_ushort4(f2bf(yc.x), f2bf(yc.y), f2bf(yc.z), f2bf(yc.w));
    }
}

// ---------------------------------------------------------------------------
// Launch
// ---------------------------------------------------------------------------
extern "C" void kernel_launch(void* const* d_in, const int* in_sizes, int n_in,
                              void* d_out, int out_size, void* d_ws, size_t ws_size,
                              hipStream_t stream)
{
    const float* x       = (const float*)d_in[0];
    const float* spa_val = (const float*)d_in[1];
    const float* spa_vec = (const float*)d_in[2];
    const float* tem_val = (const float*)d_in[3];
    const float* tem_vec = (const float*)d_in[4];
    const int*   adj     = (const int*)  d_in[5];
    const float* Wq = (const float*)d_in[6];  const float* bq = (const float*)d_in[7];
    const float* Wk = (const float*)d_in[8];  const float* bk = (const float*)d_in[9];
    const float* Wv = (const float*)d_in[10]; const float* bv = (const float*)d_in[11];
    const float* Wo = (const float*)d_in[12]; const float* bo = (const float*)d_in[13];
    const float* w_proj = (const float*)d_in[14];
    const float* b_proj = (const float*)d_in[15];
    const float* gamma  = (const float*)d_in[16];
    const float* beta   = (const float*)d_in[17];
    const float* W1 = (const float*)d_in[18]; const float* b1 = (const float*)d_in[19];
    const float* W2 = (const float*)d_in[20]; const float* b2 = (const float*)d_in[21];

    float* out = (float*)d_out;
    float* ws  = (float*)d_ws;

    const size_t R = (size_t)ROWS * FF;   // 6,291,456

    // ws layout (floats)
    float* bufQ = ws;
    float* bufK = ws + R;
    float* bufV = ws + 2 * R;
    ushort* whi = (ushort*)(ws + 3 * R);           // 6 * 262144 ushorts
    ushort* wlo = whi + 6 * 262144;                // 2 * 262144 ushorts (wq, wk)
    float* Mbuf = ws + 3 * R + (6 * 262144 + 2 * 262144) / 2;   // 98,304 floats
    int*   mtop = (int*)(Mbuf + (size_t)H_ * BTOT * NN);        // 5,184 ints

    // d_out scratch timeline: [xh|xl] -> [attnout|vbf16] -> [h1b|..] -> final
    ushort* xh  = (ushort*)d_out;
    ushort* xl  = xh + R;
    ushort* attnout = xh;        // after x_ dead
    ushort* vbf = xl;            // second half
    ushort* h1b = xh;            // first half (attnout dead after Wo gemm)

    // 1. x_ -> bf16 hi/lo planes
    add_pos_bf16<<<(ROWS * FF / 4) / 256, 256, 0, stream>>>(
        x, spa_val, spa_vec, tem_val, tem_vec, xh, xl);

    // 2. weight pre-convert
    wconv_kernel<<<dim3(256, 6), 256, 0, stream>>>(Wq, Wk, Wv, Wo, W1, W2, whi, wlo);

    // 3. Q/K/V projections
    const int NG = (ROWS / GBM) * (FF / GBN);   // 192 * 4 = 768
    gemm_mfma2<1, 0, 0><<<NG, 256, 0, stream>>>(xh, xl, whi, wlo, bq, nullptr, bufQ, nullptr);
    gemm_mfma2<1, 0, 0><<<NG, 256, 0, stream>>>(xh, xl, whi + 262144, wlo + 262144, bk, nullptr, bufK, nullptr);
    gemm_mfma2<0, 0, 0><<<NG, 256, 0, stream>>>(xh, nullptr, whi + 2 * 262144, nullptr, bv, nullptr, bufV, nullptr);

    // 4. M scores + top-27
    qks_M_kernel<<<(H_ * BTOT * NN) / 4, 256, 0, stream>>>(
        bufQ, bufK, adj, w_proj, b_proj, Mbuf);
    topk_kernel<<<H_ * BTOT, 64, 0, stream>>>(Mbuf, mtop);

    // 5. fused attention -> attnout (bf16)
    fused_attn<<<H_ * BTOT, 512, 0, stream>>>(bufQ, bufK, bufV, mtop, attnout);

    // 6. output projection + LN + FFN
    gemm_mfma2<0, 0, 0><<<NG, 256, 0, stream>>>(attnout, nullptr, whi + 3 * 262144, nullptr, bo, nullptr, bufQ, nullptr);
    ln_kernel<1, 1><<<ROWS / 4, 256, 0, stream>>>(bufQ, gamma, beta, bufK, vbf, ROWS);
    gemm_mfma2<0, 1, 1><<<NG, 256, 0, stream>>>(vbf, nullptr, whi + 4 * 262144, nullptr, b1, nullptr, nullptr, h1b);
    gemm_mfma2<0, 2, 0><<<NG, 256, 0, stream>>>(h1b, nullptr, whi + 5 * 262144, nullptr, b2, bufK, bufV, nullptr);
    ln_kernel<0, 0><<<ROWS / 4, 256, 0, stream>>>(bufV, nullptr, nullptr, out, nullptr, ROWS);
}

// Round 5
// 234.868 us; speedup vs baseline: 4.4287x; 1.0075x over previous
//
#include <hip/hip_runtime.h>
#include <math.h>

// Problem constants
#define H_    8
#define DH    64
#define NN    512
#define KADJ  16
#define FF    512      // H_*Dh
#define BTOT  24       // B*T
#define ROWS  12288    // B*T*N
#define SN_   27
#define EPS_  1e-5f

typedef short short8 __attribute__((ext_vector_type(8)));
typedef float f32x4  __attribute__((ext_vector_type(4)));

__device__ __forceinline__ ushort f2bf(float x) {
    uint u = __float_as_uint(x);
    u += 0x7FFFu + ((u >> 16) & 1u);
    return (ushort)(u >> 16);
}
__device__ __forceinline__ float bf2f(ushort h) {
    return __uint_as_float(((uint)h) << 16);
}
__device__ __forceinline__ void pack_hilo(float4 a, float4 b, short8& hi, short8& lo) {
    float v[8] = {a.x, a.y, a.z, a.w, b.x, b.y, b.z, b.w};
    #pragma unroll
    for (int j = 0; j < 8; ++j) {
        ushort h = f2bf(v[j]);
        hi[j] = (short)h;
        lo[j] = (short)f2bf(v[j] - bf2f(h));
    }
}

// async global->LDS, 16B per lane; LDS dest = wave-uniform base + lane*16
__device__ __forceinline__ void gload_lds16(const ushort* g, ushort* l) {
    __builtin_amdgcn_global_load_lds(
        (const __attribute__((address_space(1))) unsigned int*)g,
        (__attribute__((address_space(3))) unsigned int*)l,
        16, 0, 0);
}

// ---------------------------------------------------------------------------
// Kernel 1: x_ = x + pos, emitted directly as bf16 hi/lo planes
// ---------------------------------------------------------------------------
__global__ __launch_bounds__(256) void add_pos_bf16(
    const float* __restrict__ x,
    const float* __restrict__ spa_val, const float* __restrict__ spa_vec,
    const float* __restrict__ tem_val, const float* __restrict__ tem_vec,
    ushort* __restrict__ xh, ushort* __restrict__ xl)
{
    int i = blockIdx.x * 256 + threadIdx.x;   // float4 index, 1,572,864 total
    int f4  = i & 127;
    int row = i >> 7;
    int n   = row & (NN - 1);

    float4 xv = reinterpret_cast<const float4*>(x)[i];
    float4 sv = reinterpret_cast<const float4*>(spa_vec)[n * 128 + f4];
    float4 tv = reinterpret_cast<const float4*>(tem_vec)[n * 128 + f4];
    float4 se = reinterpret_cast<const float4*>(spa_val)[f4];
    float4 te = reinterpret_cast<const float4*>(tem_val)[f4];
    float r0 = xv.x + sv.x * se.x + tv.x * te.x;
    float r1 = xv.y + sv.y * se.y + tv.y * te.y;
    float r2 = xv.z + sv.z * se.z + tv.z * te.z;
    float r3 = xv.w + sv.w * se.w + tv.w * te.w;
    ushort h0 = f2bf(r0), h1 = f2bf(r1), h2 = f2bf(r2), h3 = f2bf(r3);
    reinterpret_cast<ushort4*>(xh)[i] = make_ushort4(h0, h1, h2, h3);
    reinterpret_cast<ushort4*>(xl)[i] = make_ushort4(
        f2bf(r0 - bf2f(h0)), f2bf(r1 - bf2f(h1)),
        f2bf(r2 - bf2f(h2)), f2bf(r3 - bf2f(h3)));
}

// ---------------------------------------------------------------------------
// Kernel 2: weight pre-convert: 6 weights -> hi planes; lo planes for w0,w1
// ---------------------------------------------------------------------------
__global__ __launch_bounds__(256) void wconv_kernel(
    const float* __restrict__ w0, const float* __restrict__ w1,
    const float* __restrict__ w2, const float* __restrict__ w3,
    const float* __restrict__ w4, const float* __restrict__ w5,
    ushort* __restrict__ whi, ushort* __restrict__ wlo)
{
    const int wi = blockIdx.y;
    const float* W = wi == 0 ? w0 : wi == 1 ? w1 : wi == 2 ? w2 :
                     wi == 3 ? w3 : wi == 4 ? w4 : w5;
    int i = blockIdx.x * 256 + threadIdx.x;   // 0..65535 float4
    float4 v = reinterpret_cast<const float4*>(W)[i];
    ushort h0 = f2bf(v.x), h1 = f2bf(v.y), h2 = f2bf(v.z), h3 = f2bf(v.w);
    reinterpret_cast<ushort4*>(whi + (size_t)wi * 262144)[i] =
        make_ushort4(h0, h1, h2, h3);
    if (wi < 2) {
        reinterpret_cast<ushort4*>(wlo + (size_t)wi * 262144)[i] =
            make_ushort4(f2bf(v.x - bf2f(h0)), f2bf(v.y - bf2f(h1)),
                         f2bf(v.z - bf2f(h2)), f2bf(v.w - bf2f(h3)));
    }
}

// ---------------------------------------------------------------------------
// Kernel 3: MFMA GEMM, m97 structure. C = A[M,512] * W[512,512]^T + bias
// Tile 64(M) x 128(N) x 64(K). 256 threads, 4 waves (2m x 2n), wave 32x64.
// global_load_lds staging, linear LDS dest + XOR-swizzled source; ds_read
// applies the same swizzle: slot ^= (row&7)  ->  2-way max (free).
// SPLIT=1: hi/lo planes interleaved in slots 0-3/4-7 of each 128B LDS row,
//          BK=32, 16 steps, 3 MFMA (hh+hl+lh) per fragment pair.
// EPI: 0 none, 1 relu, 2 +addsrc.  OUTBF: bf16 output to Cb else fp32 to Cf.
// Grid: 768 blocks (192 row-tiles x 4 col-tiles), XCD-swizzled.
// ---------------------------------------------------------------------------
#define GBM 64
#define GBN 128

template <int SPLIT, int EPI, int OUTBF>
__global__ __launch_bounds__(256, 2) void gemm_mfma2(
    const ushort* __restrict__ Ah, const ushort* __restrict__ Al,
    const ushort* __restrict__ Wh, const ushort* __restrict__ Wl,
    const float* __restrict__ bias, const float* __restrict__ addsrc,
    float* __restrict__ Cf, ushort* __restrict__ Cb)
{
    __shared__ ushort sA[GBM * 64];   //  8 KB
    __shared__ ushort sB[GBN * 64];   // 16 KB

    const int nx  = gridDim.x >> 3;
    const int bid = blockIdx.x;
    const int lt  = (bid & 7) * nx + (bid >> 3);
    const int rowBase = (lt >> 2) * GBM;
    const int colBase = (lt & 3) * GBN;

    const int tid  = threadIdx.x;
    const int lane = tid & 63;
    const int wid  = tid >> 6;
    const int q    = lane >> 4;     // 0..3
    const int fr   = lane & 15;
    const int wm   = wid & 1;       // row half (32)
    const int wn   = wid >> 1;      // col half (64)

    const int kadv = SPLIT ? 32 : 64;
    const ushort* asrc[2];
    const ushort* bsrc[4];
    #pragma unroll
    for (int c = 0; c < 2; ++c) {   // A tile: 8KB, wave covers 2KB
        const int p   = wid * 2048 + c * 1024 + lane * 16;
        const int row = p >> 7;
        const int ss  = ((p >> 4) & 7) ^ (row & 7);
        if (!SPLIT)
            asrc[c] = Ah + (size_t)(rowBase + row) * FF + ss * 8;
        else
            asrc[c] = (ss < 4)
                ? Ah + (size_t)(rowBase + row) * FF + ss * 8
                : Al + (size_t)(rowBase + row) * FF + (ss - 4) * 8;
    }
    #pragma unroll
    for (int c = 0; c < 4; ++c) {   // B tile: 16KB, wave covers 4KB
        const int p   = wid * 4096 + c * 1024 + lane * 16;
        const int row = p >> 7;
        const int ss  = ((p >> 4) & 7) ^ (row & 7);
        if (!SPLIT)
            bsrc[c] = Wh + (size_t)(colBase + row) * FF + ss * 8;
        else
            bsrc[c] = (ss < 4)
                ? Wh + (size_t)(colBase + row) * FF + ss * 8
                : Wl + (size_t)(colBase + row) * FF + (ss - 4) * 8;
    }

    f32x4 acc[2][4];
    #pragma unroll
    for (int mi = 0; mi < 2; ++mi)
        #pragma unroll
        for (int ni = 0; ni < 4; ++ni) acc[mi][ni] = (f32x4){0.f, 0.f, 0.f, 0.f};

    const int NSTEP = SPLIT ? 16 : 8;
    const int swz = fr & 7;

    for (int step = 0; step < NSTEP; ++step) {
        #pragma unroll
        for (int c = 0; c < 2; ++c) {
            gload_lds16(asrc[c], &sA[wid * 1024 + c * 512]);
            asrc[c] += kadv;
        }
        #pragma unroll
        for (int c = 0; c < 4; ++c) {
            gload_lds16(bsrc[c], &sB[wid * 2048 + c * 512]);
            bsrc[c] += kadv;
        }
        __syncthreads();   // drains vmcnt -> staged tile visible

        if (!SPLIT) {
            #pragma unroll
            for (int ksub = 0; ksub < 2; ++ksub) {
                const int kq = ksub * 4 + q;
                short8 af[2], bf[4];
                #pragma unroll
                for (int mi = 0; mi < 2; ++mi)
                    af[mi] = *(const short8*)&sA[(wm * 32 + mi * 16 + fr) * 64 +
                                                 ((kq ^ swz) << 3)];
                #pragma unroll
                for (int ni = 0; ni < 4; ++ni)
                    bf[ni] = *(const short8*)&sB[(wn * 64 + ni * 16 + fr) * 64 +
                                                 ((kq ^ swz) << 3)];
                #pragma unroll
                for (int mi = 0; mi < 2; ++mi)
                    #pragma unroll
                    for (int ni = 0; ni < 4; ++ni)
                        acc[mi][ni] = __builtin_amdgcn_mfma_f32_16x16x32_bf16(
                            af[mi], bf[ni], acc[mi][ni], 0, 0, 0);
            }
        } else {
            short8 ah[2], bh[4], t[4];
            #pragma unroll
            for (int mi = 0; mi < 2; ++mi)
                ah[mi] = *(const short8*)&sA[(wm * 32 + mi * 16 + fr) * 64 +
                                             ((q ^ swz) << 3)];
            #pragma unroll
            for (int ni = 0; ni < 4; ++ni)
                bh[ni] = *(const short8*)&sB[(wn * 64 + ni * 16 + fr) * 64 +
                                             ((q ^ swz) << 3)];
            // hh
            #pragma unroll
            for (int mi = 0; mi < 2; ++mi)
                #pragma unroll
                for (int ni = 0; ni < 4; ++ni)
                    acc[mi][ni] = __builtin_amdgcn_mfma_f32_16x16x32_bf16(
                        ah[mi], bh[ni], acc[mi][ni], 0, 0, 0);
            // hl
            #pragma unroll
            for (int ni = 0; ni < 4; ++ni)
                t[ni] = *(const short8*)&sB[(wn * 64 + ni * 16 + fr) * 64 +
                                            (((q + 4) ^ swz) << 3)];
            #pragma unroll
            for (int mi = 0; mi < 2; ++mi)
                #pragma unroll
                for (int ni = 0; ni < 4; ++ni)
                    acc[mi][ni] = __builtin_amdgcn_mfma_f32_16x16x32_bf16(
                        ah[mi], t[ni], acc[mi][ni], 0, 0, 0);
            // lh
            #pragma unroll
            for (int mi = 0; mi < 2; ++mi)
                t[mi] = *(const short8*)&sA[(wm * 32 + mi * 16 + fr) * 64 +
                                            (((q + 4) ^ swz) << 3)];
            #pragma unroll
            for (int mi = 0; mi < 2; ++mi)
                #pragma unroll
                for (int ni = 0; ni < 4; ++ni)
                    acc[mi][ni] = __builtin_amdgcn_mfma_f32_16x16x32_bf16(
                        t[mi], bh[ni], acc[mi][ni], 0, 0, 0);
        }
        __syncthreads();   // all reads done before next stage overwrites
    }

    // epilogue: C/D layout col=lane&15, row=(lane>>4)*4+reg
    #pragma unroll
    for (int mi = 0; mi < 2; ++mi)
        #pragma unroll
        for (int ni = 0; ni < 4; ++ni) {
            const int col = colBase + wn * 64 + ni * 16 + fr;
            const float bcol = bias[col];
            #pragma unroll
            for (int r = 0; r < 4; ++r) {
                const int row = rowBase + wm * 32 + mi * 16 + q * 4 + r;
                float v = acc[mi][ni][r] + bcol;
                if (EPI == 1) v = fmaxf(v, 0.0f);
                if (EPI == 2) v += addsrc[(size_t)row * FF + col];
                if (OUTBF) Cb[(size_t)row * FF + col] = f2bf(v);
                else       Cf[(size_t)row * FF + col] = v;
            }
        }
}

// ---------------------------------------------------------------------------
// Kernel 4: qks + M, wave per (h,bt,n), lane = d
// ---------------------------------------------------------------------------
__global__ __launch_bounds__(256) void qks_M_kernel(
    const float* __restrict__ Q, const float* __restrict__ K,
    const int* __restrict__ adj, const float* __restrict__ w_proj,
    const float* __restrict__ b_proj, float* __restrict__ Mout)
{
    const int w = blockIdx.x * 4 + (threadIdx.x >> 6);
    const int lane = threadIdx.x & 63;
    const int n   = w & (NN - 1);
    const int hbt = w >> 9;
    const int h   = hbt / BTOT;
    const int bt  = hbt % BTOT;

    float s = 0.0f;
    #pragma unroll
    for (int k = 0; k < KADJ; ++k) {
        const int j = adj[n * KADJ + k];
        s += w_proj[k] * K[((size_t)(bt * NN + j)) * FF + h * DH + lane];
    }
    float t = Q[((size_t)(bt * NN + n)) * FF + h * DH + lane] * s;
    #pragma unroll
    for (int o = 32; o; o >>= 1) t += __shfl_xor(t, o);
    if (lane == 0) Mout[(size_t)hbt * NN + n] = t + b_proj[0];
}

// ---------------------------------------------------------------------------
// Kernel 5: top-27 per group, one wave per group
// ---------------------------------------------------------------------------
__global__ __launch_bounds__(64) void topk_kernel(
    const float* __restrict__ M, int* __restrict__ mtop)
{
    const int g = blockIdx.x;
    __shared__ float vals[NN];
    const int lane = threadIdx.x;
    for (int i = lane; i < NN; i += 64) vals[i] = M[(size_t)g * NN + i];
    __syncthreads();

    for (int s = 0; s < SN_; ++s) {
        float bv = -INFINITY;
        int bi = 1 << 30;
        for (int i = lane; i < NN; i += 64) {
            float v = vals[i];
            if (v > bv || (v == bv && i < bi)) { bv = v; bi = i; }
        }
        #pragma unroll
        for (int o = 32; o; o >>= 1) {
            float ov = __shfl_xor(bv, o);
            int   oi = __shfl_xor(bi, o);
            if (ov > bv || (ov == bv && oi < bi)) { bv = ov; bi = oi; }
        }
        if (lane == 0) {
            mtop[g * SN_ + s] = bi;
            vals[bi] = -INFINITY;
        }
        __syncthreads();
    }
}

// ---------------------------------------------------------------------------
// Kernel 6: fused attention per g = (h,bt). 512 threads = 8 waves.
// V-head staged to LDS TRANSPOSED (bf16, XOR-swizzled) -- loads issued at
// kernel entry, latency hidden under score/softmax; PV reads become single
// swizzled ds_read_b128 per k-step (was 8 strided global scalars).
// ---------------------------------------------------------------------------
__global__ __launch_bounds__(512) void fused_attn(
    const float* __restrict__ Q, const float* __restrict__ K,
    const float* __restrict__ V, const int* __restrict__ mtop,
    ushort* __restrict__ attnout)
{
    __shared__ ushort P_lds[32 * 512];    // 32 KB, XOR-swizzled by row
    __shared__ ushort Vt_lds[64 * 512];   // 64 KB, Vt[d][n], XOR-swizzled by d
    __shared__ float red0[8][32];
    __shared__ float red1[8][32];
    __shared__ float val_lds[32][68];
    __shared__ int   cp_lds[NN];
    __shared__ int   mt[32];

    const int g = blockIdx.x;
    const int h = g / BTOT, bt = g % BTOT;
    const int tid = threadIdx.x;
    const int wave = tid >> 6, lane = tid & 63;
    const int q = lane >> 4, c = lane & 15;
    const size_t base_bt = (size_t)bt * NN * FF;
    const int hcol = h * DH;

    if (tid < 32) mt[tid] = mtop[g * SN_ + (tid < SN_ ? tid : 0)];

    // ---- issue V loads NOW (consumed after softmax; latency hidden) ----
    // unit u = tid + i*512: d4 = u&15 (4 d's), ng = u>>4 (4 n's at ng*4)
    float4 vreg[4][4];
    #pragma unroll
    for (int i = 0; i < 4; ++i) {
        const int u  = tid + i * 512;
        const int d4 = u & 15, ng = u >> 4;
        const float* vp = V + base_bt + (size_t)(ng * 4) * FF + hcol + d4 * 4;
        #pragma unroll
        for (int ii = 0; ii < 4; ++ii)
            vreg[i][ii] = *(const float4*)(vp + (size_t)ii * FF);
    }
    __syncthreads();   // mt visible

    // ---- A fragments: Qr rows (via mt), split hi/lo ----
    short8 afh[2][2], afl[2][2];
    #pragma unroll
    for (int m = 0; m < 2; ++m) {
        const int grow = mt[m * 16 + c];
        const float* qp = Q + base_bt + (size_t)grow * FF + hcol + q * 8;
        #pragma unroll
        for (int ks = 0; ks < 2; ++ks) {
            float4 a0 = *(const float4*)(qp + ks * 32);
            float4 a1 = *(const float4*)(qp + ks * 32 + 4);
            pack_hilo(a0, a1, afh[m][ks], afl[m][ks]);
        }
    }

    // ---- B fragments: K rows for this wave's 64-col slice ----
    const int n0 = wave * 64;
    short8 bfh[4][2], bfl[4][2];
    #pragma unroll
    for (int nt = 0; nt < 4; ++nt) {
        const int krow = n0 + nt * 16 + c;
        const float* kp = K + base_bt + (size_t)krow * FF + hcol + q * 8;
        #pragma unroll
        for (int ks = 0; ks < 2; ++ks) {
            float4 b0 = *(const float4*)(kp + ks * 32);
            float4 b1 = *(const float4*)(kp + ks * 32 + 4);
            pack_hilo(b0, b1, bfh[nt][ks], bfl[nt][ks]);
        }
    }

    // ---- scores (split: hh + hl + lh), then scale 1/8 ----
    f32x4 sc[2][4];
    #pragma unroll
    for (int m = 0; m < 2; ++m)
        #pragma unroll
        for (int nt = 0; nt < 4; ++nt) sc[m][nt] = (f32x4){0.f, 0.f, 0.f, 0.f};
    #pragma unroll
    for (int ks = 0; ks < 2; ++ks)
        #pragma unroll
        for (int m = 0; m < 2; ++m)
            #pragma unroll
            for (int nt = 0; nt < 4; ++nt) {
                sc[m][nt] = __builtin_amdgcn_mfma_f32_16x16x32_bf16(
                    afh[m][ks], bfh[nt][ks], sc[m][nt], 0, 0, 0);
                sc[m][nt] = __builtin_amdgcn_mfma_f32_16x16x32_bf16(
                    afh[m][ks], bfl[nt][ks], sc[m][nt], 0, 0, 0);
                sc[m][nt] = __builtin_amdgcn_mfma_f32_16x16x32_bf16(
                    afl[m][ks], bfh[nt][ks], sc[m][nt], 0, 0, 0);
            }
    #pragma unroll
    for (int m = 0; m < 2; ++m)
        #pragma unroll
        for (int nt = 0; nt < 4; ++nt)
            #pragma unroll
            for (int r = 0; r < 4; ++r) sc[m][nt][r] *= 0.125f;

    // ---- row max (rows = m*16 + q*4 + r) ----
    float rmax[2][4];
    #pragma unroll
    for (int m = 0; m < 2; ++m)
        #pragma unroll
        for (int r = 0; r < 4; ++r) {
            float v = sc[m][0][r];
            v = fmaxf(v, sc[m][1][r]);
            v = fmaxf(v, sc[m][2][r]);
            v = fmaxf(v, sc[m][3][r]);
            rmax[m][r] = v;
        }
    #pragma unroll
    for (int off = 1; off <= 8; off <<= 1)
        #pragma unroll
        for (int m = 0; m < 2; ++m)
            #pragma unroll
            for (int r = 0; r < 4; ++r)
                rmax[m][r] = fmaxf(rmax[m][r], __shfl_xor(rmax[m][r], off));
    if (c == 0) {
        #pragma unroll
        for (int m = 0; m < 2; ++m)
            #pragma unroll
            for (int r = 0; r < 4; ++r)
                red0[wave][m * 16 + q * 4 + r] = rmax[m][r];
    }
    __syncthreads();
    float gmax[2][4];
    #pragma unroll
    for (int m = 0; m < 2; ++m)
        #pragma unroll
        for (int r = 0; r < 4; ++r) {
            const int row = m * 16 + q * 4 + r;
            float v = red0[0][row];
            #pragma unroll
            for (int w = 1; w < 8; ++w) v = fmaxf(v, red0[w][row]);
            gmax[m][r] = v;
        }

    // ---- exp + row sum ----
    float rsum[2][4] = {};
    #pragma unroll
    for (int m = 0; m < 2; ++m)
        #pragma unroll
        for (int nt = 0; nt < 4; ++nt)
            #pragma unroll
            for (int r = 0; r < 4; ++r) {
                float e = expf(sc[m][nt][r] - gmax[m][r]);
                sc[m][nt][r] = e;
                rsum[m][r] += e;
            }
    #pragma unroll
    for (int off = 1; off <= 8; off <<= 1)
        #pragma unroll
        for (int m = 0; m < 2; ++m)
            #pragma unroll
            for (int r = 0; r < 4; ++r)
                rsum[m][r] += __shfl_xor(rsum[m][r], off);
    if (c == 0) {
        #pragma unroll
        for (int m = 0; m < 2; ++m)
            #pragma unroll
            for (int r = 0; r < 4; ++r)
                red1[wave][m * 16 + q * 4 + r] = rsum[m][r];
    }
    __syncthreads();
    #pragma unroll
    for (int m = 0; m < 2; ++m)
        #pragma unroll
        for (int r = 0; r < 4; ++r) {
            const int row = m * 16 + q * 4 + r;
            float s = red1[0][row];
            #pragma unroll
            for (int w = 1; w < 8; ++w) s += red1[w][row];
            const float inv = 1.0f / s;
            #pragma unroll
            for (int nt = 0; nt < 4; ++nt) sc[m][nt][r] *= inv;
        }

    // ---- cp argmax over rows < 27, per column ----
    #pragma unroll
    for (int nt = 0; nt < 4; ++nt) {
        float bv = -INFINITY;
        int bi = 1 << 30;
        #pragma unroll
        for (int m = 0; m < 2; ++m)
            #pragma unroll
            for (int r = 0; r < 4; ++r) {
                const int row = m * 16 + q * 4 + r;
                if (row < SN_) {
                    float v = sc[m][nt][r];
                    if (v > bv) { bv = v; bi = row; }
                }
            }
        #pragma unroll
        for (int off = 16; off <= 32; off <<= 1) {
            float ov = __shfl_xor(bv, off);
            int   oi = __shfl_xor(bi, off);
            if (ov > bv || (ov == bv && oi < bi)) { bv = ov; bi = oi; }
        }
        if (q == 0) cp_lds[n0 + nt * 16 + c] = bi;
    }

    // ---- write P (bf16) to swizzled LDS ----
    #pragma unroll
    for (int m = 0; m < 2; ++m)
        #pragma unroll
        for (int nt = 0; nt < 4; ++nt)
            #pragma unroll
            for (int r = 0; r < 4; ++r) {
                const int row = m * 16 + q * 4 + r;
                const int col = n0 + nt * 16 + c;
                P_lds[(row * 512 + col) ^ ((row & 7) << 3)] = f2bf(sc[m][nt][r]);
            }

    // ---- transpose-write V into Vt_lds (vreg waitcnt lands here) ----
    #pragma unroll
    for (int i = 0; i < 4; ++i) {
        const int u  = tid + i * 512;
        const int d4 = u & 15, ng = u >> 4;
        const int n0v = ng * 4;
        #pragma unroll
        for (int j = 0; j < 4; ++j) {
            const int d = d4 * 4 + j;
            ushort4 t;
            t.x = f2bf(((const float*)&vreg[i][0])[j]);
            t.y = f2bf(((const float*)&vreg[i][1])[j]);
            t.z = f2bf(((const float*)&vreg[i][2])[j]);
            t.w = f2bf(((const float*)&vreg[i][3])[j]);
            const int addr = (d * 512 + n0v) ^ ((d & 7) << 3);
            *(ushort4*)&Vt_lds[addr] = t;
        }
    }
    __syncthreads();

    // ---- PV: wave = (msel, dtile); k = n in 16 steps of 32 ----
    const int msel = wave >> 2, dt = wave & 3;
    const int dcol = dt * 16 + c;              // 0..63 within head
    const int prow = msel * 16 + c;
    const int pswz = (prow & 7) << 3;
    const int vswz = (dcol & 7) << 3;
    f32x4 acc = (f32x4){0.f, 0.f, 0.f, 0.f};
    for (int kstep = 0; kstep < 16; ++kstep) {
        short8 a = *(const short8*)&P_lds[(prow * 512 + kstep * 32 + q * 8) ^ pswz];
        short8 b = *(const short8*)&Vt_lds[(dcol * 512 + kstep * 32 + q * 8) ^ vswz];
        acc = __builtin_amdgcn_mfma_f32_16x16x32_bf16(a, b, acc, 0, 0, 0);
    }
    #pragma unroll
    for (int r = 0; r < 4; ++r)
        val_lds[msel * 16 + q * 4 + r][dt * 16 + c] = acc[r];
    __syncthreads();

    // ---- scatter: attnout[n][hcol+d] = val[cp[n]][d] (bf16) ----
    #pragma unroll
    for (int pass = 0; pass < 8; ++pass) {
        const int n  = pass * 64 + (tid >> 3);
        const int s  = cp_lds[n];
        const int d0 = (tid & 7) * 8;
        const float* vr = &val_lds[s][d0];
        uint4 u;
        u.x = (uint)f2bf(vr[0]) | ((uint)f2bf(vr[1]) << 16);
        u.y = (uint)f2bf(vr[2]) | ((uint)f2bf(vr[3]) << 16);
        u.z = (uint)f2bf(vr[4]) | ((uint)f2bf(vr[5]) << 16);
        u.w = (uint)f2bf(vr[6]) | ((uint)f2bf(vr[7]) << 16);
        *(uint4*)(attnout + base_bt + (size_t)n * FF + hcol + d0) = u;
    }
}

// ---------------------------------------------------------------------------
// Kernel 7: LayerNorm over last dim. BFOUT adds a bf16 copy of the result.
// ---------------------------------------------------------------------------
template <int AFFINE, int BFOUT>
__global__ __launch_bounds__(256) void ln_kernel(
    const float* __restrict__ X, const float* __restrict__ g,
    const float* __restrict__ b, float* __restrict__ Yf,
    ushort* __restrict__ Yb, int rows)
{
    const int row = blockIdx.x * 4 + (threadIdx.x >> 6);
    if (row >= rows) return;
    const int lane = threadIdx.x & 63;
    const float4* x4 = reinterpret_cast<const float4*>(X + (size_t)row * FF);
    float4 a = x4[lane];
    float4 c = x4[lane + 64];
    float s = a.x + a.y + a.z + a.w + c.x + c.y + c.z + c.w;
    float q = a.x * a.x + a.y * a.y + a.z * a.z + a.w * a.w +
              c.x * c.x + c.y * c.y + c.z * c.z + c.w * c.w;
    #pragma unroll
    for (int o = 32; o; o >>= 1) {
        s += __shfl_xor(s, o);
        q += __shfl_xor(q, o);
    }
    const float mu   = s * (1.0f / FF);
    const float var  = q * (1.0f / FF) - mu * mu;
    const float rstd = 1.0f / sqrtf(var + EPS_);

    float4 ya, yc;
    ya.x = (a.x - mu) * rstd; ya.y = (a.y - mu) * rstd;
    ya.z = (a.z - mu) * rstd; ya.w = (a.w - mu) * rstd;
    yc.x = (c.x - mu) * rstd; yc.y = (c.y - mu) * rstd;
    yc.z = (c.z - mu) * rstd; yc.w = (c.w - mu) * rstd;
    if (AFFINE) {
        float4 ga = reinterpret_cast<const float4*>(g)[lane];
        float4 gc = reinterpret_cast<const float4*>(g)[lane + 64];
        float4 ba = reinterpret_cast<const float4*>(b)[lane];
        float4 bc = reinterpret_cast<const float4*>(b)[lane + 64];
        ya.x = ya.x * ga.x + ba.x; ya.y = ya.y * ga.y + ba.y;
        ya.z = ya.z * ga.z + ba.z; ya.w = ya.w * ga.w + ba.w;
        yc.x = yc.x * gc.x + bc.x; yc.y = yc.y * gc.y + bc.y;
        yc.z = yc.z * gc.z + bc.z; yc.w = yc.w * gc.w + bc.w;
    }
    float4* y4 = reinterpret_cast<float4*>(Yf + (size_t)row * FF);
    y4[lane]      = ya;
    y4[lane + 64] = yc;
    if (BFOUT) {
        ushort4* yb = reinterpret_cast<ushort4*>(Yb + (size_t)row * FF);
        yb[lane] = make_ushort4(f2bf(ya.x), f2bf(ya.y), f2bf(ya.z), f2bf(ya.w));
        yb[lane + 64] = make_ushort4(f2bf(yc.x), f2bf(yc.y), f2bf(yc.z), f2bf(yc.w));
    }
}

// ---------------------------------------------------------------------------
// Launch
// ---------------------------------------------------------------------------
extern "C" void kernel_launch(void* const* d_in, const int* in_sizes, int n_in,
                              void* d_out, int out_size, void* d_ws, size_t ws_size,
                              hipStream_t stream)
{
    const float* x       = (const float*)d_in[0];
    const float* spa_val = (const float*)d_in[1];
    const float* spa_vec = (const float*)d_in[2];
    const float* tem_val = (const float*)d_in[3];
    const float* tem_vec = (const float*)d_in[4];
    const int*   adj     = (const int*)  d_in[5];
    const float* Wq = (const float*)d_in[6];  const float* bq = (const float*)d_in[7];
    const float* Wk = (const float*)d_in[8];  const float* bk = (const float*)d_in[9];
    const float* Wv = (const float*)d_in[10]; const float* bv = (const float*)d_in[11];
    const float* Wo = (const float*)d_in[12]; const float* bo = (const float*)d_in[13];
    const float* w_proj = (const float*)d_in[14];
    const float* b_proj = (const float*)d_in[15];
    const float* gamma  = (const float*)d_in[16];
    const float* beta   = (const float*)d_in[17];
    const float* W1 = (const float*)d_in[18]; const float* b1 = (const float*)d_in[19];
    const float* W2 = (const float*)d_in[20]; const float* b2 = (const float*)d_in[21];

    float* out = (float*)d_out;
    float* ws  = (float*)d_ws;

    const size_t R = (size_t)ROWS * FF;   // 6,291,456

    // ws layout (floats)
    float* bufQ = ws;
    float* bufK = ws + R;
    float* bufV = ws + 2 * R;
    ushort* whi = (ushort*)(ws + 3 * R);           // 6 * 262144 ushorts
    ushort* wlo = whi + 6 * 262144;                // 2 * 262144 ushorts (wq, wk)
    float* Mbuf = ws + 3 * R + (6 * 262144 + 2 * 262144) / 2;   // 98,304 floats
    int*   mtop = (int*)(Mbuf + (size_t)H_ * BTOT * NN);        // 5,184 ints

    // d_out scratch timeline: [xh|xl] -> [attnout|vbf16] -> [h1b|..] -> final
    ushort* xh  = (ushort*)d_out;
    ushort* xl  = xh + R;
    ushort* attnout = xh;        // after x_ dead
    ushort* vbf = xl;            // second half
    ushort* h1b = xh;            // first half (attnout dead after Wo gemm)

    // 1. x_ -> bf16 hi/lo planes
    add_pos_bf16<<<(ROWS * FF / 4) / 256, 256, 0, stream>>>(
        x, spa_val, spa_vec, tem_val, tem_vec, xh, xl);

    // 2. weight pre-convert
    wconv_kernel<<<dim3(256, 6), 256, 0, stream>>>(Wq, Wk, Wv, Wo, W1, W2, whi, wlo);

    // 3. Q/K/V projections
    const int NG = (ROWS / GBM) * (FF / GBN);   // 192 * 4 = 768
    gemm_mfma2<1, 0, 0><<<NG, 256, 0, stream>>>(xh, xl, whi, wlo, bq, nullptr, bufQ, nullptr);
    gemm_mfma2<1, 0, 0><<<NG, 256, 0, stream>>>(xh, xl, whi + 262144, wlo + 262144, bk, nullptr, bufK, nullptr);
    gemm_mfma2<0, 0, 0><<<NG, 256, 0, stream>>>(xh, nullptr, whi + 2 * 262144, nullptr, bv, nullptr, bufV, nullptr);

    // 4. M scores + top-27
    qks_M_kernel<<<(H_ * BTOT * NN) / 4, 256, 0, stream>>>(
        bufQ, bufK, adj, w_proj, b_proj, Mbuf);
    topk_kernel<<<H_ * BTOT, 64, 0, stream>>>(Mbuf, mtop);

    // 5. fused attention -> attnout (bf16)
    fused_attn<<<H_ * BTOT, 512, 0, stream>>>(bufQ, bufK, bufV, mtop, attnout);

    // 6. output projection + LN + FFN
    gemm_mfma2<0, 0, 0><<<NG, 256, 0, stream>>>(attnout, nullptr, whi + 3 * 262144, nullptr, bo, nullptr, bufQ, nullptr);
    ln_kernel<1, 1><<<ROWS / 4, 256, 0, stream>>>(bufQ, gamma, beta, bufK, vbf, ROWS);
    gemm_mfma2<0, 1, 1><<<NG, 256, 0, stream>>>(vbf, nullptr, whi + 4 * 262144, nullptr, b1, nullptr, nullptr, h1b);
    gemm_mfma2<0, 2, 0><<<NG, 256, 0, stream>>>(h1b, nullptr, whi + 5 * 262144, nullptr, b2, bufK, bufV, nullptr);
    ln_kernel<0, 0><<<ROWS / 4, 256, 0, stream>>>(bufV, nullptr, nullptr, out, nullptr, ROWS);
}